// Round 1
// baseline (1377.596 us; speedup 1.0000x reference)
//
#include <hip/hip_runtime.h>
#include <hip/hip_bf16.h>
#include <math.h>

// Problem constants
#define BB 8
#define CIN 256
#define FI 64
#define HW 4096
#define C8 8
#define EPS 1e-5f

// ---------------------------------------------------------------------------
// K1: psi = relu(BN(Wg@g) + BN(Wx@x))   [B,64,4096]
// grid (64,8) blocks of 256; block = all 64 out-ch x 64 pixels
// ---------------------------------------------------------------------------
__global__ __launch_bounds__(256) void k_psi(
    const float* __restrict__ g, const float* __restrict__ x,
    const float* __restrict__ Wg, const float* __restrict__ Wgb,
    const float* __restrict__ gg, const float* __restrict__ gbeta,
    const float* __restrict__ gm, const float* __restrict__ gv,
    const float* __restrict__ Wx, const float* __restrict__ Wxb,
    const float* __restrict__ xg, const float* __restrict__ xbeta,
    const float* __restrict__ xm, const float* __restrict__ xv,
    float* __restrict__ psi)
{
    const int tid = threadIdx.x;
    const int tx = tid & 63, ty = tid >> 6;
    const int b = blockIdx.y;
    const int p0 = blockIdx.x * 64;
    const int oty = __builtin_amdgcn_readfirstlane(ty * 16);

    __shared__ float tin[16][64];

    float acc[2][16];
#pragma unroll
    for (int i = 0; i < 16; ++i) { acc[0][i] = 0.f; acc[1][i] = 0.f; }

    for (int sidx = 0; sidx < 2; ++sidx) {
        const float* src = sidx ? x : g;
        const float* W   = sidx ? Wx : Wg;
        for (int k0 = 0; k0 < CIN; k0 += 16) {
            __syncthreads();
#pragma unroll
            for (int r = 0; r < 4; ++r) {
                int kk = ty + 4 * r;
                tin[kk][tx] = src[((size_t)b * CIN + (k0 + kk)) * HW + p0 + tx];
            }
            __syncthreads();
#pragma unroll
            for (int kk = 0; kk < 16; ++kk) {
                float v = tin[kk][tx];
#pragma unroll
                for (int i = 0; i < 16; ++i)
                    acc[sidx][i] += W[(oty + i) * CIN + k0 + kk] * v;
            }
        }
    }

#pragma unroll
    for (int i = 0; i < 16; ++i) {
        int o = oty + i;
        float ig = gg[o] * rsqrtf(gv[o] + EPS);
        float ix = xg[o] * rsqrtf(xv[o] + EPS);
        float vg = (acc[0][i] + Wgb[o] - gm[o]) * ig + gbeta[o];
        float vx = (acc[1][i] + Wxb[o] - xm[o]) * ix + xbeta[o];
        float pv = vg + vx;
        psi[((size_t)b * FI + o) * HW + p0 + tx] = pv > 0.f ? pv : 0.f;
    }
}

// ---------------------------------------------------------------------------
// K2: fb,fc,fd = per-pixel conv1x1 of psi with [8+8+64, 64] weights
// grid (64,8) x 256
// ---------------------------------------------------------------------------
__global__ __launch_bounds__(256) void k_fbcd(
    const float* __restrict__ psi,
    const float* __restrict__ pbw, const float* __restrict__ pbb,
    const float* __restrict__ pcw, const float* __restrict__ pcb,
    const float* __restrict__ pdw, const float* __restrict__ pdb,
    float* __restrict__ fb, float* __restrict__ fc, float* __restrict__ fd)
{
    const int tid = threadIdx.x, tx = tid & 63, ty = tid >> 6;
    const int b = blockIdx.y, p0 = blockIdx.x * 64;
    __shared__ float tpsi[64][65];
    __shared__ float WL[80][64];
    __shared__ float bL[80];

    for (int t = tid; t < 5120; t += 256) {
        int row = t >> 6, col = t & 63;
        float w;
        if (row < 8)       w = pbw[row * 64 + col];
        else if (row < 16) w = pcw[(row - 8) * 64 + col];
        else               w = pdw[(row - 16) * 64 + col];
        WL[row][col] = w;
    }
    if (tid < 80) bL[tid] = (tid < 8) ? pbb[tid] : (tid < 16 ? pcb[tid - 8] : pdb[tid - 16]);
#pragma unroll
    for (int r = 0; r < 16; ++r) {
        int c = ty * 16 + r;
        tpsi[c][tx] = psi[((size_t)b * FI + c) * HW + p0 + tx];
    }
    __syncthreads();

    const int r0 = __builtin_amdgcn_readfirstlane(ty * 20);
    float acc[20];
#pragma unroll
    for (int i = 0; i < 20; ++i) acc[i] = 0.f;
    for (int c = 0; c < 64; ++c) {
        float v = tpsi[c][tx];
#pragma unroll
        for (int i = 0; i < 20; ++i) acc[i] += WL[r0 + i][c] * v;
    }
#pragma unroll
    for (int i = 0; i < 20; ++i) {
        int row = r0 + i;
        float o = acc[i] + bL[row];
        if (row < 8)       fb[((size_t)b * C8 + row) * HW + p0 + tx] = o;
        else if (row < 16) fc[((size_t)b * C8 + (row - 8)) * HW + p0 + tx] = o;
        else               fd[((size_t)b * FI + (row - 16)) * HW + p0 + tx] = o;
    }
}

// ---------------------------------------------------------------------------
// K3a: partial Gram G[i,d] = sum_p psi[i,p] psi[d,p] over pixel slice
// grid (8 slices, 8 b) x 256 -> Gp[s][b][64][64]
// ---------------------------------------------------------------------------
__global__ __launch_bounds__(256) void k_gram(
    const float* __restrict__ psi, float* __restrict__ Gp)
{
    const int tid = threadIdx.x, tx = tid & 63, ty = tid >> 6;
    const int s = blockIdx.x, b = blockIdx.y;
    __shared__ float tp[64][65];
    float acc[16];
#pragma unroll
    for (int i = 0; i < 16; ++i) acc[i] = 0.f;
    const int ity = __builtin_amdgcn_readfirstlane(ty * 16);

    for (int pc = 0; pc < 8; ++pc) {
        int p0 = s * 512 + pc * 64;
        __syncthreads();
#pragma unroll
        for (int r = 0; r < 16; ++r) {
            int c = ty * 16 + r;
            tp[c][tx] = psi[((size_t)b * FI + c) * HW + p0 + tx];
        }
        __syncthreads();
#pragma unroll 16
        for (int pp = 0; pp < 64; ++pp) {
            float vd = tp[tx][pp];
#pragma unroll
            for (int i = 0; i < 16; ++i) acc[i] += tp[ity + i][pp] * vd;
        }
    }
#pragma unroll
    for (int i = 0; i < 16; ++i)
        Gp[((size_t)(s * 8 + b) * 64 + (ity + i)) * 64 + tx] = acc[i];
}

// ---------------------------------------------------------------------------
// K3b: CAM softmax of (rowmax - G) over last axis -> att[b][64][64]
// grid 8 x 256 (wave = one group of 16 rows, lane = column)
// ---------------------------------------------------------------------------
__global__ __launch_bounds__(256) void k_camsm(
    const float* __restrict__ Gp, float* __restrict__ att)
{
    const int tid = threadIdx.x, d = tid & 63, ty = tid >> 6;
    const int b = blockIdx.x;
#pragma unroll 1
    for (int r = 0; r < 16; ++r) {
        int i = ty * 16 + r;
        float gsum = 0.f;
#pragma unroll
        for (int s = 0; s < 8; ++s) gsum += Gp[((size_t)(s * 8 + b) * 64 + i) * 64 + d];
        float M = gsum;
#pragma unroll
        for (int msk = 1; msk < 64; msk <<= 1) M = fmaxf(M, __shfl_xor(M, msk));
        float a = M - gsum;
        float m2 = a;
#pragma unroll
        for (int msk = 1; msk < 64; msk <<= 1) m2 = fmaxf(m2, __shfl_xor(m2, msk));
        float p = __expf(a - m2);
        float ssum = p;
#pragma unroll
        for (int msk = 1; msk < 64; msk <<= 1) ssum += __shfl_xor(ssum, msk);
        att[((size_t)b * 64 + i) * 64 + d] = p / ssum;
    }
}

// ---------------------------------------------------------------------------
// K5: PAM flash attention. Q=fb^T [4096,8], K=fc^T, V=fd^T [4096,64].
// grid (64 qtiles, 8 b) x 256. lane tx = query, ty = jj-quarter of chunk.
// Oatt[b][c][i] = sum_j softmax_j(Q_i . K_j) * V[j][c]
// ---------------------------------------------------------------------------
__global__ __launch_bounds__(256) void k_pam(
    const float* __restrict__ fb, const float* __restrict__ fc,
    const float* __restrict__ fd, float* __restrict__ Oatt)
{
    const int tid = threadIdx.x, tx = tid & 63, ty = tid >> 6;
    const int b = blockIdx.y, i0 = blockIdx.x * 64;
    __shared__ float Ks[64][8];    // [jj][k] transposed, row = 32B aligned
    __shared__ float Vs[64][64];   // [c][jj]
    __shared__ float Mp[4][64];
    __shared__ float Lp[4][64];

    float4 q0, q1;
    {
        float qt[8];
#pragma unroll
        for (int k = 0; k < 8; ++k) qt[k] = fb[((size_t)b * C8 + k) * HW + i0 + tx];
        q0 = make_float4(qt[0], qt[1], qt[2], qt[3]);
        q1 = make_float4(qt[4], qt[5], qt[6], qt[7]);
    }
    float Op[64];
#pragma unroll
    for (int c = 0; c < 64; ++c) Op[c] = 0.f;
    float m = -1e30f, l = 0.f;
    const int j1 = ty * 16;

    for (int jc = 0; jc < 64; ++jc) {
        const int j0 = jc * 64;
        __syncthreads();
#pragma unroll
        for (int rr = 0; rr < 2; ++rr) {
            int t2 = tid + rr * 256;
            int k = t2 >> 6, jj = t2 & 63;
            Ks[jj][k] = fc[((size_t)b * C8 + k) * HW + j0 + jj];
        }
#pragma unroll
        for (int r = 0; r < 16; ++r) {
            int c = ty + 4 * r;
            Vs[c][tx] = fd[((size_t)b * FI + c) * HW + j0 + tx];
        }
        __syncthreads();

        float sv[16];
        float cmax = -1e30f;
#pragma unroll
        for (int r = 0; r < 16; ++r) {
            int jj = j1 + r;
            const float4 k0 = *(const float4*)&Ks[jj][0];
            const float4 k1 = *(const float4*)&Ks[jj][4];
            float s = q0.x * k0.x + q0.y * k0.y + q0.z * k0.z + q0.w * k0.w
                    + q1.x * k1.x + q1.y * k1.y + q1.z * k1.z + q1.w * k1.w;
            sv[r] = s;
            cmax = fmaxf(cmax, s);
        }
        Mp[ty][tx] = cmax;
        __syncthreads();
        float mnew = fmaxf(m, fmaxf(fmaxf(Mp[0][tx], Mp[1][tx]),
                                    fmaxf(Mp[2][tx], Mp[3][tx])));
        float scale = __expf(m - mnew);
        float psum = 0.f;
#pragma unroll
        for (int r = 0; r < 16; ++r) {
            sv[r] = __expf(sv[r] - mnew);
            psum += sv[r];
        }
        // Op[c] = Op[c]*scale + sum_{jj in my quarter} p[jj] * V[c][jj]
#pragma unroll
        for (int c = 0; c < 64; ++c) {
            const float4 v0 = *(const float4*)&Vs[c][j1];
            const float4 v1 = *(const float4*)&Vs[c][j1 + 4];
            const float4 v2 = *(const float4*)&Vs[c][j1 + 8];
            const float4 v3 = *(const float4*)&Vs[c][j1 + 12];
            float t = sv[0] * v0.x + sv[1] * v0.y + sv[2] * v0.z + sv[3] * v0.w
                    + sv[4] * v1.x + sv[5] * v1.y + sv[6] * v1.z + sv[7] * v1.w
                    + sv[8] * v2.x + sv[9] * v2.y + sv[10] * v2.z + sv[11] * v2.w
                    + sv[12] * v3.x + sv[13] * v3.y + sv[14] * v3.z + sv[15] * v3.w;
            Op[c] = Op[c] * scale + t;
        }
        Lp[ty][tx] = psum;
        __syncthreads();
        l = l * scale + (Lp[0][tx] + Lp[1][tx] + Lp[2][tx] + Lp[3][tx]);
        m = mnew;
    }

    // reduce the 4 jj-partials across ty groups via Vs, then store O/l
    __syncthreads();
#pragma unroll
    for (int ph = 0; ph < 4; ++ph) {
        if (ty == ph) {
#pragma unroll
            for (int c = 0; c < 64; ++c) {
                if (ph == 0) Vs[c][tx] = Op[c];
                else         Vs[c][tx] += Op[c];
            }
        }
        __syncthreads();
    }
    float rl = 1.f / l;
#pragma unroll
    for (int r = 0; r < 16; ++r) {
        int c = ty * 16 + r;
        Oatt[((size_t)b * FI + c) * HW + i0 + tx] = Vs[c][tx] * rl;
    }
}

// ---------------------------------------------------------------------------
// K4: cam apply + pam combine + psi-conv + BN + sigmoid + x * da
// grid (64,8) x 256
// ---------------------------------------------------------------------------
__global__ __launch_bounds__(256) void k_final(
    const float* __restrict__ psi, const float* __restrict__ att,
    const float* __restrict__ Oatt, const float* __restrict__ x,
    const float* __restrict__ psiw, const float* __restrict__ psib,
    const float* __restrict__ pg, const float* __restrict__ pbeta,
    const float* __restrict__ pm, const float* __restrict__ pv,
    const float* __restrict__ alpha, const float* __restrict__ camb,
    float* __restrict__ out)
{
    const int tid = threadIdx.x, tx = tid & 63, ty = tid >> 6;
    const int b = blockIdx.y, p0 = blockIdx.x * 64;
    __shared__ float tp[64][65];
    __shared__ float A[64][64];
    __shared__ float Zp[4][64];

#pragma unroll
    for (int r = 0; r < 16; ++r) {
        int c = ty * 16 + r;
        tp[c][tx] = psi[((size_t)b * FI + c) * HW + p0 + tx];
        A[c][tx]  = att[((size_t)b * 64 + c) * 64 + tx];
    }
    __syncthreads();

    const float al = alpha[0], cb = camb[0];
    const int c0 = __builtin_amdgcn_readfirstlane(ty * 16);
    float acc[16];
#pragma unroll
    for (int i = 0; i < 16; ++i) acc[i] = 0.f;
#pragma unroll 16
    for (int d = 0; d < 64; ++d) {
        float v = tp[d][tx];
#pragma unroll
        for (int i = 0; i < 16; ++i) acc[i] += A[c0 + i][d] * v;
    }
    float z = 0.f;
#pragma unroll
    for (int i = 0; i < 16; ++i) {
        int c = c0 + i;
        float ps  = tp[c][tx];
        float cam = cb * acc[i] + ps;
        float oa  = Oatt[((size_t)b * FI + c) * HW + p0 + tx];
        float pam = al * oa + ps;
        z += psiw[c] * (cam * pam);
    }
    Zp[ty][tx] = z;
    __syncthreads();
    float zt = Zp[0][tx] + Zp[1][tx] + Zp[2][tx] + Zp[3][tx] + psib[0];
    float inv = pg[0] * rsqrtf(pv[0] + EPS);
    float gate = (zt - pm[0]) * inv + pbeta[0];
    float da = 1.f / (1.f + __expf(-gate));

#pragma unroll 8
    for (int r = 0; r < 64; ++r) {
        int cl = ty + 4 * r;
        size_t idx = ((size_t)b * CIN + cl) * HW + p0 + tx;
        out[idx] = x[idx] * da;
    }
}

// ---------------------------------------------------------------------------
extern "C" void kernel_launch(void* const* d_in, const int* in_sizes, int n_in,
                              void* d_out, int out_size, void* d_ws, size_t ws_size,
                              hipStream_t stream)
{
    const float* g     = (const float*)d_in[0];
    const float* x     = (const float*)d_in[1];
    const float* Wg_w  = (const float*)d_in[2];
    const float* Wg_b  = (const float*)d_in[3];
    const float* bng_g = (const float*)d_in[4];
    const float* bng_b = (const float*)d_in[5];
    const float* bng_m = (const float*)d_in[6];
    const float* bng_v = (const float*)d_in[7];
    const float* Wx_w  = (const float*)d_in[8];
    const float* Wx_b  = (const float*)d_in[9];
    const float* bnx_g = (const float*)d_in[10];
    const float* bnx_b = (const float*)d_in[11];
    const float* bnx_m = (const float*)d_in[12];
    const float* bnx_v = (const float*)d_in[13];
    const float* psi_w = (const float*)d_in[14];
    const float* psi_b = (const float*)d_in[15];
    const float* bnp_g = (const float*)d_in[16];
    const float* bnp_b = (const float*)d_in[17];
    const float* bnp_m = (const float*)d_in[18];
    const float* bnp_v = (const float*)d_in[19];
    const float* pb_w  = (const float*)d_in[20];
    const float* pb_b  = (const float*)d_in[21];
    const float* pc_w  = (const float*)d_in[22];
    const float* pc_b  = (const float*)d_in[23];
    const float* pd_w  = (const float*)d_in[24];
    const float* pd_b  = (const float*)d_in[25];
    const float* alpha = (const float*)d_in[26];
    const float* camb  = (const float*)d_in[27];
    float* out = (float*)d_out;

    float* ws  = (float*)d_ws;
    float* psi = ws;                  // 2,097,152
    float* fb  = ws + 2097152;        //   262,144
    float* fc  = ws + 2359296;        //   262,144
    float* fd  = ws + 2621440;        // 2,097,152
    float* Gp  = ws + 4718592;        //   262,144
    float* att = ws + 4980736;        //    32,768
    float* Oa  = ws + 5013504;        // 2,097,152  (end 7,110,656 floats = 28.4 MB)

    k_psi<<<dim3(64, 8), 256, 0, stream>>>(g, x, Wg_w, Wg_b, bng_g, bng_b, bng_m, bng_v,
                                           Wx_w, Wx_b, bnx_g, bnx_b, bnx_m, bnx_v, psi);
    k_fbcd<<<dim3(64, 8), 256, 0, stream>>>(psi, pb_w, pb_b, pc_w, pc_b, pd_w, pd_b,
                                            fb, fc, fd);
    k_gram<<<dim3(8, 8), 256, 0, stream>>>(psi, Gp);
    k_camsm<<<dim3(8), 256, 0, stream>>>(Gp, att);
    k_pam<<<dim3(64, 8), 256, 0, stream>>>(fb, fc, fd, Oa);
    k_final<<<dim3(64, 8), 256, 0, stream>>>(psi, att, Oa, x, psi_w, psi_b,
                                             bnp_g, bnp_b, bnp_m, bnp_v, alpha, camb, out);
}

// Round 2
// 770.576 us; speedup vs baseline: 1.7877x; 1.7877x over previous
//
#include <hip/hip_runtime.h>
#include <hip/hip_bf16.h>
#include <math.h>

// Problem constants
#define BB 8
#define CIN 256
#define FI 64
#define HW 4096
#define C8 8
#define EPS 1e-5f

typedef __attribute__((ext_vector_type(8))) short bf16x8;
typedef __attribute__((ext_vector_type(4))) float f32x4;

static __device__ __forceinline__ unsigned short f2b(float x) {
    unsigned u = __builtin_bit_cast(unsigned, x);
    return (unsigned short)((u + 0x8000u) >> 16);
}
static __device__ __forceinline__ unsigned pk2(float a, float b) {
    unsigned ua = __builtin_bit_cast(unsigned, a);
    unsigned ub = __builtin_bit_cast(unsigned, b);
    return ((ua + 0x8000u) >> 16) | ((ub + 0x8000u) & 0xffff0000u);
}

// ---------------------------------------------------------------------------
// K1: psi = relu(BN(Wg@g) + BN(Wx@x))   [B,64,4096]
// ---------------------------------------------------------------------------
__global__ __launch_bounds__(256) void k_psi(
    const float* __restrict__ g, const float* __restrict__ x,
    const float* __restrict__ Wg, const float* __restrict__ Wgb,
    const float* __restrict__ gg, const float* __restrict__ gbeta,
    const float* __restrict__ gm, const float* __restrict__ gv,
    const float* __restrict__ Wx, const float* __restrict__ Wxb,
    const float* __restrict__ xg, const float* __restrict__ xbeta,
    const float* __restrict__ xm, const float* __restrict__ xv,
    float* __restrict__ psi)
{
    const int tid = threadIdx.x;
    const int tx = tid & 63, ty = tid >> 6;
    const int b = blockIdx.y;
    const int p0 = blockIdx.x * 64;
    const int oty = __builtin_amdgcn_readfirstlane(ty * 16);

    __shared__ float tin[16][64];

    float acc[2][16];
#pragma unroll
    for (int i = 0; i < 16; ++i) { acc[0][i] = 0.f; acc[1][i] = 0.f; }

    for (int sidx = 0; sidx < 2; ++sidx) {
        const float* src = sidx ? x : g;
        const float* W   = sidx ? Wx : Wg;
        for (int k0 = 0; k0 < CIN; k0 += 16) {
            __syncthreads();
#pragma unroll
            for (int r = 0; r < 4; ++r) {
                int kk = ty + 4 * r;
                tin[kk][tx] = src[((size_t)b * CIN + (k0 + kk)) * HW + p0 + tx];
            }
            __syncthreads();
#pragma unroll
            for (int kk = 0; kk < 16; ++kk) {
                float v = tin[kk][tx];
#pragma unroll
                for (int i = 0; i < 16; ++i)
                    acc[sidx][i] += W[(oty + i) * CIN + k0 + kk] * v;
            }
        }
    }

#pragma unroll
    for (int i = 0; i < 16; ++i) {
        int o = oty + i;
        float ig = gg[o] * rsqrtf(gv[o] + EPS);
        float ix = xg[o] * rsqrtf(xv[o] + EPS);
        float vg = (acc[0][i] + Wgb[o] - gm[o]) * ig + gbeta[o];
        float vx = (acc[1][i] + Wxb[o] - xm[o]) * ix + xbeta[o];
        float pv = vg + vx;
        psi[((size_t)b * FI + o) * HW + p0 + tx] = pv > 0.f ? pv : 0.f;
    }
}

// ---------------------------------------------------------------------------
// K2: fb,fc,fd = per-pixel conv1x1 of psi with [8+8+64, 64] weights
// ---------------------------------------------------------------------------
__global__ __launch_bounds__(256) void k_fbcd(
    const float* __restrict__ psi,
    const float* __restrict__ pbw, const float* __restrict__ pbb,
    const float* __restrict__ pcw, const float* __restrict__ pcb,
    const float* __restrict__ pdw, const float* __restrict__ pdb,
    float* __restrict__ fb, float* __restrict__ fc, float* __restrict__ fd)
{
    const int tid = threadIdx.x, tx = tid & 63, ty = tid >> 6;
    const int b = blockIdx.y, p0 = blockIdx.x * 64;
    __shared__ float tpsi[64][65];
    __shared__ float WL[80][64];
    __shared__ float bL[80];

    for (int t = tid; t < 5120; t += 256) {
        int row = t >> 6, col = t & 63;
        float w;
        if (row < 8)       w = pbw[row * 64 + col];
        else if (row < 16) w = pcw[(row - 8) * 64 + col];
        else               w = pdw[(row - 16) * 64 + col];
        WL[row][col] = w;
    }
    if (tid < 80) bL[tid] = (tid < 8) ? pbb[tid] : (tid < 16 ? pcb[tid - 8] : pdb[tid - 16]);
#pragma unroll
    for (int r = 0; r < 16; ++r) {
        int c = ty * 16 + r;
        tpsi[c][tx] = psi[((size_t)b * FI + c) * HW + p0 + tx];
    }
    __syncthreads();

    const int r0 = __builtin_amdgcn_readfirstlane(ty * 20);
    float acc[20];
#pragma unroll
    for (int i = 0; i < 20; ++i) acc[i] = 0.f;
    for (int c = 0; c < 64; ++c) {
        float v = tpsi[c][tx];
#pragma unroll
        for (int i = 0; i < 20; ++i) acc[i] += WL[r0 + i][c] * v;
    }
#pragma unroll
    for (int i = 0; i < 20; ++i) {
        int row = r0 + i;
        float o = acc[i] + bL[row];
        if (row < 8)       fb[((size_t)b * C8 + row) * HW + p0 + tx] = o;
        else if (row < 16) fc[((size_t)b * C8 + (row - 8)) * HW + p0 + tx] = o;
        else               fd[((size_t)b * FI + (row - 16)) * HW + p0 + tx] = o;
    }
}

// ---------------------------------------------------------------------------
// K3a: partial Gram over pixel slices
// ---------------------------------------------------------------------------
__global__ __launch_bounds__(256) void k_gram(
    const float* __restrict__ psi, float* __restrict__ Gp)
{
    const int tid = threadIdx.x, tx = tid & 63, ty = tid >> 6;
    const int s = blockIdx.x, b = blockIdx.y;
    __shared__ float tp[64][65];
    float acc[16];
#pragma unroll
    for (int i = 0; i < 16; ++i) acc[i] = 0.f;
    const int ity = __builtin_amdgcn_readfirstlane(ty * 16);

    for (int pc = 0; pc < 8; ++pc) {
        int p0 = s * 512 + pc * 64;
        __syncthreads();
#pragma unroll
        for (int r = 0; r < 16; ++r) {
            int c = ty * 16 + r;
            tp[c][tx] = psi[((size_t)b * FI + c) * HW + p0 + tx];
        }
        __syncthreads();
#pragma unroll 16
        for (int pp = 0; pp < 64; ++pp) {
            float vd = tp[tx][pp];
#pragma unroll
            for (int i = 0; i < 16; ++i) acc[i] += tp[ity + i][pp] * vd;
        }
    }
#pragma unroll
    for (int i = 0; i < 16; ++i)
        Gp[((size_t)(s * 8 + b) * 64 + (ity + i)) * 64 + tx] = acc[i];
}

// ---------------------------------------------------------------------------
// K3b: CAM softmax
// ---------------------------------------------------------------------------
__global__ __launch_bounds__(256) void k_camsm(
    const float* __restrict__ Gp, float* __restrict__ att)
{
    const int tid = threadIdx.x, d = tid & 63, ty = tid >> 6;
    const int b = blockIdx.x;
#pragma unroll 1
    for (int r = 0; r < 16; ++r) {
        int i = ty * 16 + r;
        float gsum = 0.f;
#pragma unroll
        for (int s = 0; s < 8; ++s) gsum += Gp[((size_t)(s * 8 + b) * 64 + i) * 64 + d];
        float M = gsum;
#pragma unroll
        for (int msk = 1; msk < 64; msk <<= 1) M = fmaxf(M, __shfl_xor(M, msk));
        float a = M - gsum;
        float m2 = a;
#pragma unroll
        for (int msk = 1; msk < 64; msk <<= 1) m2 = fmaxf(m2, __shfl_xor(m2, msk));
        float p = __expf(a - m2);
        float ssum = p;
#pragma unroll
        for (int msk = 1; msk < 64; msk <<= 1) ssum += __shfl_xor(ssum, msk);
        att[((size_t)b * 64 + i) * 64 + d] = p / ssum;
    }
}

// ---------------------------------------------------------------------------
// K5: PAM flash attention via bf16 MFMA.
// Q=fb^T [4096,8], K=fc^T [4096,8], V=fd^T [4096,64]; O^T stored [64,4096].
// grid (8 batch, 64 qtile) x 256 (batch on blockIdx.x for XCD L2 locality).
// Each wave owns 16 queries. Per 64-key chunk:
//   S^T = K@Q^T  (4 MFMA, K-dim 8 padded to 32 with zeros)
//   online softmax in-register (C layout: col=lane&15=query, row=quad*4+reg=key)
//   P^T -> per-wave LDS (C-layout -> B-layout transform), O^T += V^T@P^T (8 MFMA)
// ---------------------------------------------------------------------------
__global__ __launch_bounds__(256) void k_pam(
    const float* __restrict__ fb, const float* __restrict__ fc,
    const float* __restrict__ fd, float* __restrict__ Oatt)
{
    const int tid  = threadIdx.x;
    const int lane = tid & 63;
    const int w    = tid >> 6;      // wave 0..3
    const int n    = lane & 15;     // MFMA col index (query)
    const int quad = lane >> 4;
    const int b    = blockIdx.x;    // batch -> XCD-local fc/fd working set
    const int i0   = blockIdx.y * 64;

    // rows padded for 16B-aligned b128 frag reads, <=2-way bank aliasing
    __shared__ unsigned short Ks[64][40];     // [key][k]  cols 8..31 zero
    __shared__ unsigned short Qs[64][40];     // [query][k] cols 8..31 zero
    __shared__ unsigned short Vs[64][72];     // [chan][key]
    __shared__ unsigned short Ps[4][16][72];  // per-wave P^T [q_local][key]

    // zero-init the padded K-dim of Qs/Ks once (cols 8..31 stay zero forever)
    for (int t = tid; t < 64 * 20; t += 256) {
        ((unsigned*)Ks)[t] = 0u;
        ((unsigned*)Qs)[t] = 0u;
    }
    __syncthreads();
    // stage Q for this block's 64 queries: fb [8][HW] -> Qs[q][k]
    {
        int k = tid >> 5, q0 = (tid & 31) * 2;
        float2 v = *(const float2*)&fb[((size_t)b * C8 + k) * HW + i0 + q0];
        Qs[q0][k]     = f2b(v.x);
        Qs[q0 + 1][k] = f2b(v.y);
    }
    __syncthreads();
    // B-operand frag for Q^T: lane(quad,n): frag[j] = Q[w*16+n][quad*8+j]
    const bf16x8 qfrag = *(const bf16x8*)&Qs[w * 16 + n][quad * 8];

    f32x4 oacc[4];
#pragma unroll
    for (int mt = 0; mt < 4; ++mt) oacc[mt] = (f32x4){0.f, 0.f, 0.f, 0.f};
    float m = -1e30f, l = 0.f;

    for (int jc = 0; jc < 64; ++jc) {
        const int j0 = jc * 64;
        __syncthreads();   // previous iteration's Ks/Vs readers done
        // stage K chunk: fc [8][64] -> Ks[key][k]
        {
            int k = tid >> 5, q0 = (tid & 31) * 2;
            float2 v = *(const float2*)&fc[((size_t)b * C8 + k) * HW + j0 + q0];
            Ks[q0][k]     = f2b(v.x);
            Ks[q0 + 1][k] = f2b(v.y);
        }
        // stage V chunk: fd [64][64] -> Vs[c][j] (packed b32 writes)
#pragma unroll
        for (int r = 0; r < 8; ++r) {
            int c  = (tid >> 5) + r * 8;
            int j2 = (tid & 31) * 2;
            float2 v = *(const float2*)&fd[((size_t)b * FI + c) * HW + j0 + j2];
            *(unsigned*)&Vs[c][j2] = pk2(v.x, v.y);
        }
        __syncthreads();

        // S^T tiles: A = K rows (m = lane&15), B = qfrag
        f32x4 s[4];
#pragma unroll
        for (int mt = 0; mt < 4; ++mt) {
            bf16x8 af = *(const bf16x8*)&Ks[mt * 16 + n][quad * 8];
            s[mt] = __builtin_amdgcn_mfma_f32_16x16x32_bf16(
                        af, qfrag, (f32x4){0.f, 0.f, 0.f, 0.f}, 0, 0, 0);
        }

        // online softmax: lane holds keys {mt*16+quad*4+r} for query w*16+n
        float cmax = -1e30f;
#pragma unroll
        for (int mt = 0; mt < 4; ++mt) {
            cmax = fmaxf(cmax, fmaxf(fmaxf(s[mt][0], s[mt][1]),
                                     fmaxf(s[mt][2], s[mt][3])));
        }
        cmax = fmaxf(cmax, __shfl_xor(cmax, 16));
        cmax = fmaxf(cmax, __shfl_xor(cmax, 32));
        float mnew  = fmaxf(m, cmax);
        float scale = __expf(m - mnew);
        float psum  = 0.f;
        unsigned pw[4][2];
#pragma unroll
        for (int mt = 0; mt < 4; ++mt) {
            float e0 = __expf(s[mt][0] - mnew), e1 = __expf(s[mt][1] - mnew);
            float e2 = __expf(s[mt][2] - mnew), e3 = __expf(s[mt][3] - mnew);
            psum += (e0 + e1) + (e2 + e3);
            pw[mt][0] = pk2(e0, e1);
            pw[mt][1] = pk2(e2, e3);
        }
        psum += __shfl_xor(psum, 16);
        psum += __shfl_xor(psum, 32);
        l = l * scale + psum;
        m = mnew;

        // P^T -> per-wave LDS (no barrier: wave-local region)
#pragma unroll
        for (int mt = 0; mt < 4; ++mt)
            *(uint2*)&Ps[w][n][mt * 16 + quad * 4] = make_uint2(pw[mt][0], pw[mt][1]);
        asm volatile("s_waitcnt lgkmcnt(0)" ::: "memory");

        // O^T = O^T*scale + V^T @ P^T
#pragma unroll
        for (int mt = 0; mt < 4; ++mt) {
            oacc[mt][0] *= scale; oacc[mt][1] *= scale;
            oacc[mt][2] *= scale; oacc[mt][3] *= scale;
        }
#pragma unroll
        for (int k0 = 0; k0 < 2; ++k0) {
            bf16x8 pf = *(const bf16x8*)&Ps[w][n][k0 * 32 + quad * 8];
#pragma unroll
            for (int mt = 0; mt < 4; ++mt) {
                bf16x8 vf = *(const bf16x8*)&Vs[mt * 16 + n][k0 * 32 + quad * 8];
                oacc[mt] = __builtin_amdgcn_mfma_f32_16x16x32_bf16(
                               vf, pf, oacc[mt], 0, 0, 0);
            }
        }
    }

    // store: D layout row = quad*4+reg = channel-in-tile, col = n = query
    const float rl = 1.f / l;
#pragma unroll
    for (int mt = 0; mt < 4; ++mt)
#pragma unroll
        for (int r = 0; r < 4; ++r) {
            int c = mt * 16 + quad * 4 + r;
            Oatt[((size_t)b * FI + c) * HW + i0 + w * 16 + n] = oacc[mt][r] * rl;
        }
}

// ---------------------------------------------------------------------------
// K4: cam apply + pam combine + psi-conv + BN + sigmoid + x * da
// ---------------------------------------------------------------------------
__global__ __launch_bounds__(256) void k_final(
    const float* __restrict__ psi, const float* __restrict__ att,
    const float* __restrict__ Oatt, const float* __restrict__ x,
    const float* __restrict__ psiw, const float* __restrict__ psib,
    const float* __restrict__ pg, const float* __restrict__ pbeta,
    const float* __restrict__ pm, const float* __restrict__ pv,
    const float* __restrict__ alpha, const float* __restrict__ camb,
    float* __restrict__ out)
{
    const int tid = threadIdx.x, tx = tid & 63, ty = tid >> 6;
    const int b = blockIdx.y, p0 = blockIdx.x * 64;
    __shared__ float tp[64][65];
    __shared__ float A[64][64];
    __shared__ float Zp[4][64];

#pragma unroll
    for (int r = 0; r < 16; ++r) {
        int c = ty * 16 + r;
        tp[c][tx] = psi[((size_t)b * FI + c) * HW + p0 + tx];
        A[c][tx]  = att[((size_t)b * 64 + c) * 64 + tx];
    }
    __syncthreads();

    const float al = alpha[0], cb = camb[0];
    const int c0 = __builtin_amdgcn_readfirstlane(ty * 16);
    float acc[16];
#pragma unroll
    for (int i = 0; i < 16; ++i) acc[i] = 0.f;
#pragma unroll 16
    for (int d = 0; d < 64; ++d) {
        float v = tp[d][tx];
#pragma unroll
        for (int i = 0; i < 16; ++i) acc[i] += A[c0 + i][d] * v;
    }
    float z = 0.f;
#pragma unroll
    for (int i = 0; i < 16; ++i) {
        int c = c0 + i;
        float ps  = tp[c][tx];
        float cam = cb * acc[i] + ps;
        float oa  = Oatt[((size_t)b * FI + c) * HW + p0 + tx];
        float pam = al * oa + ps;
        z += psiw[c] * (cam * pam);
    }
    Zp[ty][tx] = z;
    __syncthreads();
    float zt = Zp[0][tx] + Zp[1][tx] + Zp[2][tx] + Zp[3][tx] + psib[0];
    float inv = pg[0] * rsqrtf(pv[0] + EPS);
    float gate = (zt - pm[0]) * inv + pbeta[0];
    float da = 1.f / (1.f + __expf(-gate));

#pragma unroll 8
    for (int r = 0; r < 64; ++r) {
        int cl = ty + 4 * r;
        size_t idx = ((size_t)b * CIN + cl) * HW + p0 + tx;
        out[idx] = x[idx] * da;
    }
}

// ---------------------------------------------------------------------------
extern "C" void kernel_launch(void* const* d_in, const int* in_sizes, int n_in,
                              void* d_out, int out_size, void* d_ws, size_t ws_size,
                              hipStream_t stream)
{
    const float* g     = (const float*)d_in[0];
    const float* x     = (const float*)d_in[1];
    const float* Wg_w  = (const float*)d_in[2];
    const float* Wg_b  = (const float*)d_in[3];
    const float* bng_g = (const float*)d_in[4];
    const float* bng_b = (const float*)d_in[5];
    const float* bng_m = (const float*)d_in[6];
    const float* bng_v = (const float*)d_in[7];
    const float* Wx_w  = (const float*)d_in[8];
    const float* Wx_b  = (const float*)d_in[9];
    const float* bnx_g = (const float*)d_in[10];
    const float* bnx_b = (const float*)d_in[11];
    const float* bnx_m = (const float*)d_in[12];
    const float* bnx_v = (const float*)d_in[13];
    const float* psi_w = (const float*)d_in[14];
    const float* psi_b = (const float*)d_in[15];
    const float* bnp_g = (const float*)d_in[16];
    const float* bnp_b = (const float*)d_in[17];
    const float* bnp_m = (const float*)d_in[18];
    const float* bnp_v = (const float*)d_in[19];
    const float* pb_w  = (const float*)d_in[20];
    const float* pb_b  = (const float*)d_in[21];
    const float* pc_w  = (const float*)d_in[22];
    const float* pc_b  = (const float*)d_in[23];
    const float* pd_w  = (const float*)d_in[24];
    const float* pd_b  = (const float*)d_in[25];
    const float* alpha = (const float*)d_in[26];
    const float* camb  = (const float*)d_in[27];
    float* out = (float*)d_out;

    float* ws  = (float*)d_ws;
    float* psi = ws;                  // 2,097,152
    float* fb  = ws + 2097152;        //   262,144
    float* fc  = ws + 2359296;        //   262,144
    float* fd  = ws + 2621440;        // 2,097,152
    float* Gp  = ws + 4718592;        //   262,144
    float* att = ws + 4980736;        //    32,768
    float* Oa  = ws + 5013504;        // 2,097,152  (end 7,110,656 floats = 28.4 MB)

    k_psi<<<dim3(64, 8), 256, 0, stream>>>(g, x, Wg_w, Wg_b, bng_g, bng_b, bng_m, bng_v,
                                           Wx_w, Wx_b, bnx_g, bnx_b, bnx_m, bnx_v, psi);
    k_fbcd<<<dim3(64, 8), 256, 0, stream>>>(psi, pb_w, pb_b, pc_w, pc_b, pd_w, pd_b,
                                            fb, fc, fd);
    k_gram<<<dim3(8, 8), 256, 0, stream>>>(psi, Gp);
    k_camsm<<<dim3(8), 256, 0, stream>>>(Gp, att);
    k_pam<<<dim3(8, 64), 256, 0, stream>>>(fb, fc, fd, Oa);
    k_final<<<dim3(64, 8), 256, 0, stream>>>(psi, att, Oa, x, psi_w, psi_b,
                                             bnp_g, bnp_b, bnp_m, bnp_v, alpha, camb, out);
}

// Round 3
// 455.631 us; speedup vs baseline: 3.0235x; 1.6912x over previous
//
#include <hip/hip_runtime.h>
#include <hip/hip_bf16.h>
#include <math.h>

// Problem constants
#define BB 8
#define CIN 256
#define FI 64
#define HW 4096
#define C8 8
#define EPS 1e-5f

typedef __attribute__((ext_vector_type(8))) short bf16x8;
typedef __attribute__((ext_vector_type(4))) float f32x4;
typedef unsigned short u16;

static __device__ __forceinline__ u16 f2b(float x) {
    unsigned u = __builtin_bit_cast(unsigned, x);
    return (u16)((u + 0x8000u) >> 16);
}
static __device__ __forceinline__ unsigned pk2(float a, float b) {
    unsigned ua = __builtin_bit_cast(unsigned, a);
    unsigned ub = __builtin_bit_cast(unsigned, b);
    return ((ua + 0x8000u) >> 16) | ((ub + 0x8000u) & 0xffff0000u);
}

// ---------------------------------------------------------------------------
// K0: fold BN scales into conv weights.
// W'[o][k] (bf16, k<256 from Wg*inv_g, k>=256 from Wx*inv_x), C[o] fp32.
// ---------------------------------------------------------------------------
__global__ __launch_bounds__(256) void k_prep(
    const float* __restrict__ Wg, const float* __restrict__ Wgb,
    const float* __restrict__ gg, const float* __restrict__ gbeta,
    const float* __restrict__ gm, const float* __restrict__ gv,
    const float* __restrict__ Wx, const float* __restrict__ Wxb,
    const float* __restrict__ xg, const float* __restrict__ xbeta,
    const float* __restrict__ xm, const float* __restrict__ xv,
    u16* __restrict__ Wp, float* __restrict__ Cp)
{
    const int tid = threadIdx.x;
    if (tid < FI) {
        float ig = gg[tid] * rsqrtf(gv[tid] + EPS);
        float ix = xg[tid] * rsqrtf(xv[tid] + EPS);
        Cp[tid] = (Wgb[tid] - gm[tid]) * ig + gbeta[tid]
                + (Wxb[tid] - xm[tid]) * ix + xbeta[tid];
    }
    for (int idx = tid; idx < FI * 512; idx += 256) {
        int o = idx >> 9, k = idx & 511;
        float s, w;
        if (k < 256) { s = gg[o] * rsqrtf(gv[o] + EPS); w = Wg[o * 256 + k]; }
        else         { s = xg[o] * rsqrtf(xv[o] + EPS); w = Wx[o * 256 + k - 256]; }
        Wp[idx] = f2b(w * s);
    }
}

// ---------------------------------------------------------------------------
// K1: psi = relu(W' @ cat(g,x) + C) via bf16 MFMA.  [B,64,4096]
// grid (64 px-tiles, 8 b) x 256. Wave w owns pixels w*16..+15, all 64 ch.
// A-frags read directly from L2-resident W' (64 KB); B from LDS-transposed
// input tile (fp32->bf16 on stage).
// ---------------------------------------------------------------------------
__global__ __launch_bounds__(256) void k_psi(
    const float* __restrict__ g, const float* __restrict__ x,
    const u16* __restrict__ Wp, const float* __restrict__ Cp,
    float* __restrict__ psi)
{
    const int tid  = threadIdx.x;
    const int lane = tid & 63;
    const int w    = tid >> 6;
    const int n    = lane & 15;
    const int quad = lane >> 4;
    const int b    = blockIdx.y;
    const int p0   = blockIdx.x * 64;

    __shared__ u16 InT[64][72];   // [pixel][k-local], 144B row stride

    f32x4 acc[4];
#pragma unroll
    for (int mt = 0; mt < 4; ++mt) acc[mt] = (f32x4){0.f, 0.f, 0.f, 0.f};

    for (int kc = 0; kc < 8; ++kc) {
        const float* src = (kc < 4) ? g : x;
        const int ch0 = (kc & 3) * 64;
        __syncthreads();
#pragma unroll
        for (int r = 0; r < 8; ++r) {
            int ch = (tid >> 5) + r * 8;
            int px = (tid & 31) * 2;
            float2 v = *(const float2*)&src[((size_t)b * CIN + ch0 + ch) * HW + p0 + px];
            InT[px][ch]     = f2b(v.x);
            InT[px + 1][ch] = f2b(v.y);
        }
        __syncthreads();
#pragma unroll
        for (int ks = 0; ks < 2; ++ks) {
            const int kglob = kc * 64 + ks * 32;
            bf16x8 bfrag = *(const bf16x8*)&InT[w * 16 + n][ks * 32 + quad * 8];
#pragma unroll
            for (int mt = 0; mt < 4; ++mt) {
                bf16x8 af = *(const bf16x8*)&Wp[(mt * 16 + n) * 512 + kglob + quad * 8];
                acc[mt] = __builtin_amdgcn_mfma_f32_16x16x32_bf16(
                              af, bfrag, acc[mt], 0, 0, 0);
            }
        }
    }

#pragma unroll
    for (int mt = 0; mt < 4; ++mt)
#pragma unroll
        for (int r = 0; r < 4; ++r) {
            int c = mt * 16 + quad * 4 + r;
            float v = acc[mt][r] + Cp[c];
            psi[((size_t)b * FI + c) * HW + p0 + w * 16 + n] = v > 0.f ? v : 0.f;
        }
}

// ---------------------------------------------------------------------------
// K2: fb,fc,fd = per-pixel conv1x1 of psi with [8+8+64, 64] weights
// ---------------------------------------------------------------------------
__global__ __launch_bounds__(256) void k_fbcd(
    const float* __restrict__ psi,
    const float* __restrict__ pbw, const float* __restrict__ pbb,
    const float* __restrict__ pcw, const float* __restrict__ pcb,
    const float* __restrict__ pdw, const float* __restrict__ pdb,
    float* __restrict__ fb, float* __restrict__ fc, float* __restrict__ fd)
{
    const int tid = threadIdx.x, tx = tid & 63, ty = tid >> 6;
    const int b = blockIdx.y, p0 = blockIdx.x * 64;
    __shared__ float tpsi[64][65];
    __shared__ float WL[80][64];
    __shared__ float bL[80];

    for (int t = tid; t < 5120; t += 256) {
        int row = t >> 6, col = t & 63;
        float w;
        if (row < 8)       w = pbw[row * 64 + col];
        else if (row < 16) w = pcw[(row - 8) * 64 + col];
        else               w = pdw[(row - 16) * 64 + col];
        WL[row][col] = w;
    }
    if (tid < 80) bL[tid] = (tid < 8) ? pbb[tid] : (tid < 16 ? pcb[tid - 8] : pdb[tid - 16]);
#pragma unroll
    for (int r = 0; r < 16; ++r) {
        int c = ty * 16 + r;
        tpsi[c][tx] = psi[((size_t)b * FI + c) * HW + p0 + tx];
    }
    __syncthreads();

    const int r0 = __builtin_amdgcn_readfirstlane(ty * 20);
    float acc[20];
#pragma unroll
    for (int i = 0; i < 20; ++i) acc[i] = 0.f;
    for (int c = 0; c < 64; ++c) {
        float v = tpsi[c][tx];
#pragma unroll
        for (int i = 0; i < 20; ++i) acc[i] += WL[r0 + i][c] * v;
    }
#pragma unroll
    for (int i = 0; i < 20; ++i) {
        int row = r0 + i;
        float o = acc[i] + bL[row];
        if (row < 8)       fb[((size_t)b * C8 + row) * HW + p0 + tx] = o;
        else if (row < 16) fc[((size_t)b * C8 + (row - 8)) * HW + p0 + tx] = o;
        else               fd[((size_t)b * FI + (row - 16)) * HW + p0 + tx] = o;
    }
}

// ---------------------------------------------------------------------------
// K3a: partial Gram over pixel slices
// ---------------------------------------------------------------------------
__global__ __launch_bounds__(256) void k_gram(
    const float* __restrict__ psi, float* __restrict__ Gp)
{
    const int tid = threadIdx.x, tx = tid & 63, ty = tid >> 6;
    const int s = blockIdx.x, b = blockIdx.y;
    __shared__ float tp[64][65];
    float acc[16];
#pragma unroll
    for (int i = 0; i < 16; ++i) acc[i] = 0.f;
    const int ity = __builtin_amdgcn_readfirstlane(ty * 16);

    for (int pc = 0; pc < 8; ++pc) {
        int p0 = s * 512 + pc * 64;
        __syncthreads();
#pragma unroll
        for (int r = 0; r < 16; ++r) {
            int c = ty * 16 + r;
            tp[c][tx] = psi[((size_t)b * FI + c) * HW + p0 + tx];
        }
        __syncthreads();
#pragma unroll 16
        for (int pp = 0; pp < 64; ++pp) {
            float vd = tp[tx][pp];
#pragma unroll
            for (int i = 0; i < 16; ++i) acc[i] += tp[ity + i][pp] * vd;
        }
    }
#pragma unroll
    for (int i = 0; i < 16; ++i)
        Gp[((size_t)(s * 8 + b) * 64 + (ity + i)) * 64 + tx] = acc[i];
}

// ---------------------------------------------------------------------------
// K3b: CAM softmax
// ---------------------------------------------------------------------------
__global__ __launch_bounds__(256) void k_camsm(
    const float* __restrict__ Gp, float* __restrict__ att)
{
    const int tid = threadIdx.x, d = tid & 63, ty = tid >> 6;
    const int b = blockIdx.x;
#pragma unroll 1
    for (int r = 0; r < 16; ++r) {
        int i = ty * 16 + r;
        float gsum = 0.f;
#pragma unroll
        for (int s = 0; s < 8; ++s) gsum += Gp[((size_t)(s * 8 + b) * 64 + i) * 64 + d];
        float M = gsum;
#pragma unroll
        for (int msk = 1; msk < 64; msk <<= 1) M = fmaxf(M, __shfl_xor(M, msk));
        float a = M - gsum;
        float m2 = a;
#pragma unroll
        for (int msk = 1; msk < 64; msk <<= 1) m2 = fmaxf(m2, __shfl_xor(m2, msk));
        float p = __expf(a - m2);
        float ssum = p;
#pragma unroll
        for (int msk = 1; msk < 64; msk <<= 1) ssum += __shfl_xor(ssum, msk);
        att[((size_t)b * 64 + i) * 64 + d] = p / ssum;
    }
}

// ---------------------------------------------------------------------------
// K5: PAM flash attention via bf16 MFMA.
// ---------------------------------------------------------------------------
__global__ __launch_bounds__(256) void k_pam(
    const float* __restrict__ fb, const float* __restrict__ fc,
    const float* __restrict__ fd, float* __restrict__ Oatt)
{
    const int tid  = threadIdx.x;
    const int lane = tid & 63;
    const int w    = tid >> 6;      // wave 0..3
    const int n    = lane & 15;     // MFMA col index (query)
    const int quad = lane >> 4;
    const int b    = blockIdx.x;    // batch -> XCD-local fc/fd working set
    const int i0   = blockIdx.y * 64;

    __shared__ u16 Ks[64][40];     // [key][k]  cols 8..31 zero
    __shared__ u16 Qs[64][40];     // [query][k] cols 8..31 zero
    __shared__ u16 Vs[64][72];     // [chan][key]
    __shared__ u16 Ps[4][16][72];  // per-wave P^T [q_local][key]

    for (int t = tid; t < 64 * 20; t += 256) {
        ((unsigned*)Ks)[t] = 0u;
        ((unsigned*)Qs)[t] = 0u;
    }
    __syncthreads();
    {
        int k = tid >> 5, q0 = (tid & 31) * 2;
        float2 v = *(const float2*)&fb[((size_t)b * C8 + k) * HW + i0 + q0];
        Qs[q0][k]     = f2b(v.x);
        Qs[q0 + 1][k] = f2b(v.y);
    }
    __syncthreads();
    const bf16x8 qfrag = *(const bf16x8*)&Qs[w * 16 + n][quad * 8];

    f32x4 oacc[4];
#pragma unroll
    for (int mt = 0; mt < 4; ++mt) oacc[mt] = (f32x4){0.f, 0.f, 0.f, 0.f};
    float m = -1e30f, l = 0.f;

    for (int jc = 0; jc < 64; ++jc) {
        const int j0 = jc * 64;
        __syncthreads();
        {
            int k = tid >> 5, q0 = (tid & 31) * 2;
            float2 v = *(const float2*)&fc[((size_t)b * C8 + k) * HW + j0 + q0];
            Ks[q0][k]     = f2b(v.x);
            Ks[q0 + 1][k] = f2b(v.y);
        }
#pragma unroll
        for (int r = 0; r < 8; ++r) {
            int c  = (tid >> 5) + r * 8;
            int j2 = (tid & 31) * 2;
            float2 v = *(const float2*)&fd[((size_t)b * FI + c) * HW + j0 + j2];
            *(unsigned*)&Vs[c][j2] = pk2(v.x, v.y);
        }
        __syncthreads();

        f32x4 s[4];
#pragma unroll
        for (int mt = 0; mt < 4; ++mt) {
            bf16x8 af = *(const bf16x8*)&Ks[mt * 16 + n][quad * 8];
            s[mt] = __builtin_amdgcn_mfma_f32_16x16x32_bf16(
                        af, qfrag, (f32x4){0.f, 0.f, 0.f, 0.f}, 0, 0, 0);
        }

        float cmax = -1e30f;
#pragma unroll
        for (int mt = 0; mt < 4; ++mt) {
            cmax = fmaxf(cmax, fmaxf(fmaxf(s[mt][0], s[mt][1]),
                                     fmaxf(s[mt][2], s[mt][3])));
        }
        cmax = fmaxf(cmax, __shfl_xor(cmax, 16));
        cmax = fmaxf(cmax, __shfl_xor(cmax, 32));
        float mnew  = fmaxf(m, cmax);
        float scale = __expf(m - mnew);
        float psum  = 0.f;
        unsigned pw[4][2];
#pragma unroll
        for (int mt = 0; mt < 4; ++mt) {
            float e0 = __expf(s[mt][0] - mnew), e1 = __expf(s[mt][1] - mnew);
            float e2 = __expf(s[mt][2] - mnew), e3 = __expf(s[mt][3] - mnew);
            psum += (e0 + e1) + (e2 + e3);
            pw[mt][0] = pk2(e0, e1);
            pw[mt][1] = pk2(e2, e3);
        }
        psum += __shfl_xor(psum, 16);
        psum += __shfl_xor(psum, 32);
        l = l * scale + psum;
        m = mnew;

#pragma unroll
        for (int mt = 0; mt < 4; ++mt)
            *(uint2*)&Ps[w][n][mt * 16 + quad * 4] = make_uint2(pw[mt][0], pw[mt][1]);
        asm volatile("s_waitcnt lgkmcnt(0)" ::: "memory");

#pragma unroll
        for (int mt = 0; mt < 4; ++mt) {
            oacc[mt][0] *= scale; oacc[mt][1] *= scale;
            oacc[mt][2] *= scale; oacc[mt][3] *= scale;
        }
#pragma unroll
        for (int k0 = 0; k0 < 2; ++k0) {
            bf16x8 pf = *(const bf16x8*)&Ps[w][n][k0 * 32 + quad * 8];
#pragma unroll
            for (int mt = 0; mt < 4; ++mt) {
                bf16x8 vf = *(const bf16x8*)&Vs[mt * 16 + n][k0 * 32 + quad * 8];
                oacc[mt] = __builtin_amdgcn_mfma_f32_16x16x32_bf16(
                               vf, pf, oacc[mt], 0, 0, 0);
            }
        }
    }

    const float rl = 1.f / l;
#pragma unroll
    for (int mt = 0; mt < 4; ++mt)
#pragma unroll
        for (int r = 0; r < 4; ++r) {
            int c = mt * 16 + quad * 4 + r;
            Oatt[((size_t)b * FI + c) * HW + i0 + w * 16 + n] = oacc[mt][r] * rl;
        }
}

// ---------------------------------------------------------------------------
// K4: cam apply + pam combine + psi-conv + BN + sigmoid + x * da
// ---------------------------------------------------------------------------
__global__ __launch_bounds__(256) void k_final(
    const float* __restrict__ psi, const float* __restrict__ att,
    const float* __restrict__ Oatt, const float* __restrict__ x,
    const float* __restrict__ psiw, const float* __restrict__ psib,
    const float* __restrict__ pg, const float* __restrict__ pbeta,
    const float* __restrict__ pm, const float* __restrict__ pv,
    const float* __restrict__ alpha, const float* __restrict__ camb,
    float* __restrict__ out)
{
    const int tid = threadIdx.x, tx = tid & 63, ty = tid >> 6;
    const int b = blockIdx.y, p0 = blockIdx.x * 64;
    __shared__ float tp[64][65];
    __shared__ float A[64][64];
    __shared__ float Zp[4][64];

#pragma unroll
    for (int r = 0; r < 16; ++r) {
        int c = ty * 16 + r;
        tp[c][tx] = psi[((size_t)b * FI + c) * HW + p0 + tx];
        A[c][tx]  = att[((size_t)b * 64 + c) * 64 + tx];
    }
    __syncthreads();

    const float al = alpha[0], cb = camb[0];
    const int c0 = __builtin_amdgcn_readfirstlane(ty * 16);
    float acc[16];
#pragma unroll
    for (int i = 0; i < 16; ++i) acc[i] = 0.f;
#pragma unroll 16
    for (int d = 0; d < 64; ++d) {
        float v = tp[d][tx];
#pragma unroll
        for (int i = 0; i < 16; ++i) acc[i] += A[c0 + i][d] * v;
    }
    float z = 0.f;
#pragma unroll
    for (int i = 0; i < 16; ++i) {
        int c = c0 + i;
        float ps  = tp[c][tx];
        float cam = cb * acc[i] + ps;
        float oa  = Oatt[((size_t)b * FI + c) * HW + p0 + tx];
        float pam = al * oa + ps;
        z += psiw[c] * (cam * pam);
    }
    Zp[ty][tx] = z;
    __syncthreads();
    float zt = Zp[0][tx] + Zp[1][tx] + Zp[2][tx] + Zp[3][tx] + psib[0];
    float inv = pg[0] * rsqrtf(pv[0] + EPS);
    float gate = (zt - pm[0]) * inv + pbeta[0];
    float da = 1.f / (1.f + __expf(-gate));

#pragma unroll 8
    for (int r = 0; r < 64; ++r) {
        int cl = ty + 4 * r;
        size_t idx = ((size_t)b * CIN + cl) * HW + p0 + tx;
        out[idx] = x[idx] * da;
    }
}

// ---------------------------------------------------------------------------
extern "C" void kernel_launch(void* const* d_in, const int* in_sizes, int n_in,
                              void* d_out, int out_size, void* d_ws, size_t ws_size,
                              hipStream_t stream)
{
    const float* g     = (const float*)d_in[0];
    const float* x     = (const float*)d_in[1];
    const float* Wg_w  = (const float*)d_in[2];
    const float* Wg_b  = (const float*)d_in[3];
    const float* bng_g = (const float*)d_in[4];
    const float* bng_b = (const float*)d_in[5];
    const float* bng_m = (const float*)d_in[6];
    const float* bng_v = (const float*)d_in[7];
    const float* Wx_w  = (const float*)d_in[8];
    const float* Wx_b  = (const float*)d_in[9];
    const float* bnx_g = (const float*)d_in[10];
    const float* bnx_b = (const float*)d_in[11];
    const float* bnx_m = (const float*)d_in[12];
    const float* bnx_v = (const float*)d_in[13];
    const float* psi_w = (const float*)d_in[14];
    const float* psi_b = (const float*)d_in[15];
    const float* bnp_g = (const float*)d_in[16];
    const float* bnp_b = (const float*)d_in[17];
    const float* bnp_m = (const float*)d_in[18];
    const float* bnp_v = (const float*)d_in[19];
    const float* pb_w  = (const float*)d_in[20];
    const float* pb_b  = (const float*)d_in[21];
    const float* pc_w  = (const float*)d_in[22];
    const float* pc_b  = (const float*)d_in[23];
    const float* pd_w  = (const float*)d_in[24];
    const float* pd_b  = (const float*)d_in[25];
    const float* alpha = (const float*)d_in[26];
    const float* camb  = (const float*)d_in[27];
    float* out = (float*)d_out;

    float* ws  = (float*)d_ws;
    float* psi = ws;                  // 2,097,152
    float* fb  = ws + 2097152;        //   262,144
    float* fc  = ws + 2359296;        //   262,144
    float* fd  = ws + 2621440;        // 2,097,152
    float* Gp  = ws + 4718592;        //   262,144
    float* att = ws + 4980736;        //    32,768
    float* Oa  = ws + 5013504;        // 2,097,152
    u16*   Wp  = (u16*)(ws + 7110656);//    32,768 u16 = 16,384 floats
    float* Cp  = ws + 7127040;        //        64   (end ~28.5 MB)

    k_prep<<<dim3(1), 256, 0, stream>>>(Wg_w, Wg_b, bng_g, bng_b, bng_m, bng_v,
                                        Wx_w, Wx_b, bnx_g, bnx_b, bnx_m, bnx_v, Wp, Cp);
    k_psi<<<dim3(64, 8), 256, 0, stream>>>(g, x, Wp, Cp, psi);
    k_fbcd<<<dim3(64, 8), 256, 0, stream>>>(psi, pb_w, pb_b, pc_w, pc_b, pd_w, pd_b,
                                            fb, fc, fd);
    k_gram<<<dim3(8, 8), 256, 0, stream>>>(psi, Gp);
    k_camsm<<<dim3(8), 256, 0, stream>>>(Gp, att);
    k_pam<<<dim3(8, 64), 256, 0, stream>>>(fb, fc, fd, Oa);
    k_final<<<dim3(64, 8), 256, 0, stream>>>(psi, att, Oa, x, psi_w, psi_b,
                                             bnp_g, bnp_b, bnp_m, bnp_v, alpha, camb, out);
}

// Round 6
// 317.597 us; speedup vs baseline: 4.3376x; 1.4346x over previous
//
#include <hip/hip_runtime.h>
#include <hip/hip_bf16.h>
#include <math.h>

// Problem constants
#define BB 8
#define CIN 256
#define FI 64
#define HW 4096
#define C8 8
#define EPS 1e-5f

typedef __attribute__((ext_vector_type(8))) short bf16x8;
typedef __attribute__((ext_vector_type(4))) float f32x4;
typedef unsigned short u16;

static __device__ __forceinline__ u16 f2b(float x) {
    unsigned u = __builtin_bit_cast(unsigned, x);
    return (u16)((u + 0x8000u) >> 16);
}
static __device__ __forceinline__ unsigned pk2(float a, float b) {
    unsigned ua = __builtin_bit_cast(unsigned, a);
    unsigned ub = __builtin_bit_cast(unsigned, b);
    return ((ua + 0x8000u) >> 16) | ((ub + 0x8000u) & 0xffff0000u);
}
static __device__ __forceinline__ float b2f(u16 v) {
    return __builtin_bit_cast(float, ((unsigned)v) << 16);
}

// ---------------------------------------------------------------------------
// K0: fold BN into psi-conv weights (Wp bf16 [64][512], Cp fp32[64]) and
// build concatenated PAM weights (Wcat bf16 [80][64], bcat fp32[80]).
// ---------------------------------------------------------------------------
__global__ __launch_bounds__(256) void k_prep(
    const float* __restrict__ Wg, const float* __restrict__ Wgb,
    const float* __restrict__ gg, const float* __restrict__ gbeta,
    const float* __restrict__ gm, const float* __restrict__ gv,
    const float* __restrict__ Wx, const float* __restrict__ Wxb,
    const float* __restrict__ xg, const float* __restrict__ xbeta,
    const float* __restrict__ xm, const float* __restrict__ xv,
    const float* __restrict__ pbw, const float* __restrict__ pbb,
    const float* __restrict__ pcw, const float* __restrict__ pcb,
    const float* __restrict__ pdw, const float* __restrict__ pdb,
    u16* __restrict__ Wp, float* __restrict__ Cp,
    u16* __restrict__ Wcat, float* __restrict__ bcat)
{
    const int gid = blockIdx.x * 256 + threadIdx.x;
    for (int idx = gid; idx < FI * 512; idx += 4096) {
        int o = idx >> 9, k = idx & 511;
        float s, w;
        if (k < 256) { s = gg[o] * rsqrtf(gv[o] + EPS); w = Wg[o * 256 + k]; }
        else         { s = xg[o] * rsqrtf(xv[o] + EPS); w = Wx[o * 256 + k - 256]; }
        Wp[idx] = f2b(w * s);
    }
    for (int idx = gid; idx < 80 * 64; idx += 4096) {
        int row = idx >> 6, col = idx & 63;
        float w;
        if (row < 8)       w = pbw[row * 64 + col];
        else if (row < 16) w = pcw[(row - 8) * 64 + col];
        else               w = pdw[(row - 16) * 64 + col];
        Wcat[idx] = f2b(w);
    }
    if (blockIdx.x == 0) {
        int tid = threadIdx.x;
        if (tid < FI) {
            float ig = gg[tid] * rsqrtf(gv[tid] + EPS);
            float ix = xg[tid] * rsqrtf(xv[tid] + EPS);
            Cp[tid] = (Wgb[tid] - gm[tid]) * ig + gbeta[tid]
                    + (Wxb[tid] - xm[tid]) * ix + xbeta[tid];
        }
        if (tid >= 64 && tid < 144) {
            int r = tid - 64;
            bcat[r] = (r < 8) ? pbb[r] : (r < 16 ? pcb[r - 8] : pdb[r - 16]);
        }
    }
}

// ---------------------------------------------------------------------------
// K1: psi = relu(W' @ cat(g,x) + C) via bf16 MFMA.
// Emits psiB (hi) + psiLo (residual) bf16 [B][64][4096] and psiT bf16
// [B][4096][64] (hi only). psi = hi + lo reconstructs fp32-accurate values.
// ---------------------------------------------------------------------------
__global__ __launch_bounds__(256) void k_psi(
    const float* __restrict__ g, const float* __restrict__ x,
    const u16* __restrict__ Wp, const float* __restrict__ Cp,
    u16* __restrict__ psiB, u16* __restrict__ psiLo, u16* __restrict__ psiT)
{
    const int tid  = threadIdx.x;
    const int lane = tid & 63;
    const int w    = tid >> 6;
    const int n    = lane & 15;
    const int quad = lane >> 4;
    const int b    = blockIdx.y;
    const int p0   = blockIdx.x * 64;

    __shared__ u16 InT[64][72];   // staging [pixel][k-local]; reused for psiT

    f32x4 acc[4];
#pragma unroll
    for (int mt = 0; mt < 4; ++mt) acc[mt] = (f32x4){0.f, 0.f, 0.f, 0.f};

    for (int kc = 0; kc < 8; ++kc) {
        const float* src = (kc < 4) ? g : x;
        const int ch0 = (kc & 3) * 64;
        __syncthreads();
#pragma unroll
        for (int r = 0; r < 8; ++r) {
            int ch = (tid >> 5) + r * 8;
            int px = (tid & 31) * 2;
            float2 v = *(const float2*)&src[((size_t)b * CIN + ch0 + ch) * HW + p0 + px];
            InT[px][ch]     = f2b(v.x);
            InT[px + 1][ch] = f2b(v.y);
        }
        __syncthreads();
#pragma unroll
        for (int ks = 0; ks < 2; ++ks) {
            const int kglob = kc * 64 + ks * 32;
            bf16x8 bfrag = *(const bf16x8*)&InT[w * 16 + n][ks * 32 + quad * 8];
#pragma unroll
            for (int mt = 0; mt < 4; ++mt) {
                bf16x8 af = *(const bf16x8*)&Wp[(mt * 16 + n) * 512 + kglob + quad * 8];
                acc[mt] = __builtin_amdgcn_mfma_f32_16x16x32_bf16(
                              af, bfrag, acc[mt], 0, 0, 0);
            }
        }
    }

    // epilogue: bias + relu; store psiB(hi)+psiLo direct, psiT via LDS transpose
    float pv[4][4];
#pragma unroll
    for (int mt = 0; mt < 4; ++mt)
#pragma unroll
        for (int r = 0; r < 4; ++r) {
            int c = mt * 16 + quad * 4 + r;
            float v = acc[mt][r] + Cp[c];
            v = v > 0.f ? v : 0.f;
            pv[mt][r] = v;
            u16 hb = f2b(v);
            size_t idx = ((size_t)b * FI + c) * HW + p0 + w * 16 + n;
            psiB[idx]  = hb;
            psiLo[idx] = f2b(v - b2f(hb));
        }
    __syncthreads();   // done with InT staging use
#pragma unroll
    for (int mt = 0; mt < 4; ++mt) {
        *(unsigned*)&InT[w * 16 + n][mt * 16 + quad * 4]     = pk2(pv[mt][0], pv[mt][1]);
        *(unsigned*)&InT[w * 16 + n][mt * 16 + quad * 4 + 2] = pk2(pv[mt][2], pv[mt][3]);
    }
    __syncthreads();
    // 64 px rows x 64 ch = 512 bf16x8 copies (FIXED: was covering half the chans)
#pragma unroll
    for (int rep = 0; rep < 2; ++rep) {
        int t = rep * 256 + tid;
        int row = t >> 3, seg = t & 7;
        bf16x8 v = *(const bf16x8*)&InT[row][seg * 8];
        *(bf16x8*)&psiT[((size_t)b * HW + p0 + row) * FI + seg * 8] = v;
    }
}

// ---------------------------------------------------------------------------
// K2: fbcd via MFMA: D[px][out80] = psiT @ Wcat^T + bcat.
// Emits fbcT bf16 [B][4096][16] (cols 0..7=fb, 8..15=fc) and fdB bf16 [B][64][4096].
// ---------------------------------------------------------------------------
__global__ __launch_bounds__(256) void k_fbcd(
    const u16* __restrict__ psiT, const u16* __restrict__ Wcat,
    const float* __restrict__ bcat,
    u16* __restrict__ fbcT, u16* __restrict__ fdB)
{
    const int tid  = threadIdx.x;
    const int lane = tid & 63;
    const int w    = tid >> 6;
    const int n    = lane & 15;
    const int quad = lane >> 4;
    const int b    = blockIdx.y;
    const int p0   = blockIdx.x * 64;

    __shared__ u16 Tfd[64][72];   // [ch][px]
    __shared__ u16 Tbc[64][16];   // [px][out16]

    f32x4 acc[5];
#pragma unroll
    for (int nt = 0; nt < 5; ++nt) acc[nt] = (f32x4){0.f, 0.f, 0.f, 0.f};

#pragma unroll
    for (int ks = 0; ks < 2; ++ks) {
        bf16x8 af = *(const bf16x8*)&psiT[((size_t)b * HW + p0 + w * 16 + n) * FI
                                          + ks * 32 + quad * 8];
#pragma unroll
        for (int nt = 0; nt < 5; ++nt) {
            bf16x8 bf = *(const bf16x8*)&Wcat[(nt * 16 + n) * FI + ks * 32 + quad * 8];
            acc[nt] = __builtin_amdgcn_mfma_f32_16x16x32_bf16(af, bf, acc[nt], 0, 0, 0);
        }
    }

    {
        float bias = bcat[n];
#pragma unroll
        for (int r = 0; r < 4; ++r)
            Tbc[w * 16 + quad * 4 + r][n] = f2b(acc[0][r] + bias);
    }
#pragma unroll
    for (int nt = 1; nt < 5; ++nt) {
        int ch = (nt - 1) * 16 + n;
        float bias = bcat[nt * 16 + n];
        *(unsigned*)&Tfd[ch][w * 16 + quad * 4]     = pk2(acc[nt][0] + bias, acc[nt][1] + bias);
        *(unsigned*)&Tfd[ch][w * 16 + quad * 4 + 2] = pk2(acc[nt][2] + bias, acc[nt][3] + bias);
    }
    __syncthreads();
    {   // fbcT: 64 rows x 16 el, uint2 = 4 el x 4 parts
        int row = tid >> 2, part = tid & 3;
        uint2 v = *(const uint2*)&Tbc[row][part * 4];
        *(uint2*)&fbcT[((size_t)b * HW + p0 + row) * 16 + part * 4] = v;
    }
    // fdB: 64 ch x 64 px = 512 bf16x8 copies (FIXED: was OOB rows + half cols)
#pragma unroll
    for (int rep = 0; rep < 2; ++rep) {
        int t = rep * 256 + tid;
        int ch = t >> 3, seg = t & 7;
        bf16x8 v = *(const bf16x8*)&Tfd[ch][seg * 8];
        *(bf16x8*)&fdB[((size_t)b * FI + ch) * HW + p0 + seg * 8] = v;
    }
}

// ---------------------------------------------------------------------------
// K3a: Gram partials via compensated bf16 MFMA:
// G ~= hi^T hi + hi^T lo + lo^T hi  (error ~2^-18, fp32-equivalent logits).
// grid (32 slices, 8 b) x 256 -> Gp[s][b][64][64]
// ---------------------------------------------------------------------------
__global__ __launch_bounds__(256) void k_gram(
    const u16* __restrict__ psiB, const u16* __restrict__ psiLo,
    float* __restrict__ Gp)
{
    const int tid  = threadIdx.x;
    const int lane = tid & 63;
    const int w    = tid >> 6;
    const int n    = lane & 15;
    const int quad = lane >> 4;
    const int s    = blockIdx.x;
    const int b    = blockIdx.y;

    f32x4 acc[4];
#pragma unroll
    for (int nt = 0; nt < 4; ++nt) acc[nt] = (f32x4){0.f, 0.f, 0.f, 0.f};

    for (int ks = 0; ks < 4; ++ks) {
        const int k0 = s * 128 + ks * 32;
        const size_t ra = ((size_t)b * FI + w * 16 + n) * HW + k0 + quad * 8;
        bf16x8 ah = *(const bf16x8*)&psiB[ra];
        bf16x8 al = *(const bf16x8*)&psiLo[ra];
#pragma unroll
        for (int nt = 0; nt < 4; ++nt) {
            const size_t rb = ((size_t)b * FI + nt * 16 + n) * HW + k0 + quad * 8;
            bf16x8 bh = *(const bf16x8*)&psiB[rb];
            bf16x8 bl = *(const bf16x8*)&psiLo[rb];
            acc[nt] = __builtin_amdgcn_mfma_f32_16x16x32_bf16(ah, bh, acc[nt], 0, 0, 0);
            acc[nt] = __builtin_amdgcn_mfma_f32_16x16x32_bf16(ah, bl, acc[nt], 0, 0, 0);
            acc[nt] = __builtin_amdgcn_mfma_f32_16x16x32_bf16(al, bh, acc[nt], 0, 0, 0);
        }
    }
#pragma unroll
    for (int nt = 0; nt < 4; ++nt)
#pragma unroll
        for (int r = 0; r < 4; ++r) {
            int i = w * 16 + quad * 4 + r;
            Gp[(((size_t)s * 8 + b) * 64 + i) * 64 + nt * 16 + n] = acc[nt][r];
        }
}

// ---------------------------------------------------------------------------
// K3b: CAM softmax of (rowmax - G).  grid (8 b, 4 grp) x 256
// ---------------------------------------------------------------------------
__global__ __launch_bounds__(256) void k_camsm(
    const float* __restrict__ Gp, float* __restrict__ att)
{
    const int tid = threadIdx.x, d = tid & 63, ty = tid >> 6;
    const int b = blockIdx.x, grp = blockIdx.y;
#pragma unroll 1
    for (int rr = 0; rr < 4; ++rr) {
        int i = grp * 16 + ty * 4 + rr;
        float gsum = 0.f;
#pragma unroll 1
        for (int s = 0; s < 32; ++s) gsum += Gp[(((size_t)s * 8 + b) * 64 + i) * 64 + d];
        float M = gsum;
#pragma unroll
        for (int msk = 1; msk < 64; msk <<= 1) M = fmaxf(M, __shfl_xor(M, msk));
        float a = M - gsum;
        float m2 = a;
#pragma unroll
        for (int msk = 1; msk < 64; msk <<= 1) m2 = fmaxf(m2, __shfl_xor(m2, msk));
        float p = __expf(a - m2);
        float ssum = p;
#pragma unroll
        for (int msk = 1; msk < 64; msk <<= 1) ssum += __shfl_xor(ssum, msk);
        att[((size_t)b * 64 + i) * 64 + d] = p / ssum;
    }
}

// ---------------------------------------------------------------------------
// K5: PAM flash attention, bf16 MFMA, pre-converted inputs.
// Q|K from fbcT [4096][16], V from fdB [64][4096].
// grid (8 b, 64 qtile) x 256.
// ---------------------------------------------------------------------------
__global__ __launch_bounds__(256) void k_pam(
    const u16* __restrict__ fbcT, const u16* __restrict__ fdB,
    float* __restrict__ Oatt)
{
    const int tid  = threadIdx.x;
    const int lane = tid & 63;
    const int w    = tid >> 6;
    const int n    = lane & 15;
    const int quad = lane >> 4;
    const int b    = blockIdx.x;
    const int i0   = blockIdx.y * 64;

    __shared__ u16 Ks[68][8];      // [key][k0..7]; rows 64..67 zero pad (quad overread)
    __shared__ u16 Qs[64][32];     // [query][k]; cols 8..31 zero
    __shared__ u16 Vs[64][72];     // [chan][key]
    __shared__ u16 Ps[4][16][72];  // per-wave P^T [q_local][key]

    for (int t = tid; t < 64 * 16; t += 256) ((unsigned*)Qs)[t] = 0u;
    if (tid < 16) ((unsigned*)&Ks[64][0])[tid] = 0u;
    __syncthreads();
    if (tid < 64)
        *(bf16x8*)&Qs[tid][0] = *(const bf16x8*)&fbcT[((size_t)b * HW + i0 + tid) * 16];
    __syncthreads();
    const bf16x8 qfrag = *(const bf16x8*)&Qs[w * 16 + n][quad * 8];

    f32x4 oacc[4];
#pragma unroll
    for (int mt = 0; mt < 4; ++mt) oacc[mt] = (f32x4){0.f, 0.f, 0.f, 0.f};
    float m = -1e30f, l = 0.f;

    for (int jc = 0; jc < 64; ++jc) {
        const int j0 = jc * 64;
        __syncthreads();
        if (tid < 128) {   // K chunk: 64 keys x 8 u16
            int key = tid >> 1, half = tid & 1;
            uint2 v = *(const uint2*)&fbcT[((size_t)b * HW + j0 + key) * 16 + 8 + half * 4];
            *(uint2*)&Ks[key][half * 4] = v;
        }
#pragma unroll
        for (int rep = 0; rep < 2; ++rep) {   // V chunk: 64 ch x 64 keys
            int t = rep * 256 + tid;
            int ch = t >> 3, j8 = (t & 7) * 8;
            bf16x8 v = *(const bf16x8*)&fdB[((size_t)b * FI + ch) * HW + j0 + j8];
            *(bf16x8*)&Vs[ch][j8] = v;
        }
        __syncthreads();

        // S^T tiles: A = K rows (quad overread hits finite data x zero Q cols)
        f32x4 s[4];
#pragma unroll
        for (int mt = 0; mt < 4; ++mt) {
            bf16x8 af = *(const bf16x8*)&Ks[mt * 16 + n + quad][0];
            s[mt] = __builtin_amdgcn_mfma_f32_16x16x32_bf16(
                        af, qfrag, (f32x4){0.f, 0.f, 0.f, 0.f}, 0, 0, 0);
        }

        float cmax = -1e30f;
#pragma unroll
        for (int mt = 0; mt < 4; ++mt)
            cmax = fmaxf(cmax, fmaxf(fmaxf(s[mt][0], s[mt][1]),
                                     fmaxf(s[mt][2], s[mt][3])));
        cmax = fmaxf(cmax, __shfl_xor(cmax, 16));
        cmax = fmaxf(cmax, __shfl_xor(cmax, 32));
        float mnew  = fmaxf(m, cmax);
        float scale = __expf(m - mnew);
        float psum  = 0.f;
        unsigned pw[4][2];
#pragma unroll
        for (int mt = 0; mt < 4; ++mt) {
            float e0 = __expf(s[mt][0] - mnew), e1 = __expf(s[mt][1] - mnew);
            float e2 = __expf(s[mt][2] - mnew), e3 = __expf(s[mt][3] - mnew);
            psum += (e0 + e1) + (e2 + e3);
            pw[mt][0] = pk2(e0, e1);
            pw[mt][1] = pk2(e2, e3);
        }
        psum += __shfl_xor(psum, 16);
        psum += __shfl_xor(psum, 32);
        l = l * scale + psum;
        m = mnew;

#pragma unroll
        for (int mt = 0; mt < 4; ++mt)
            *(uint2*)&Ps[w][n][mt * 16 + quad * 4] = make_uint2(pw[mt][0], pw[mt][1]);
        asm volatile("s_waitcnt lgkmcnt(0)" ::: "memory");

#pragma unroll
        for (int mt = 0; mt < 4; ++mt) {
            oacc[mt][0] *= scale; oacc[mt][1] *= scale;
            oacc[mt][2] *= scale; oacc[mt][3] *= scale;
        }
#pragma unroll
        for (int k0 = 0; k0 < 2; ++k0) {
            bf16x8 pf = *(const bf16x8*)&Ps[w][n][k0 * 32 + quad * 8];
#pragma unroll
            for (int mt = 0; mt < 4; ++mt) {
                bf16x8 vf = *(const bf16x8*)&Vs[mt * 16 + n][k0 * 32 + quad * 8];
                oacc[mt] = __builtin_amdgcn_mfma_f32_16x16x32_bf16(
                               vf, pf, oacc[mt], 0, 0, 0);
            }
        }
    }

    const float rl = 1.f / l;
#pragma unroll
    for (int mt = 0; mt < 4; ++mt)
#pragma unroll
        for (int r = 0; r < 4; ++r) {
            int c = mt * 16 + quad * 4 + r;
            Oatt[((size_t)b * FI + c) * HW + i0 + w * 16 + n] = oacc[mt][r] * rl;
        }
}

// ---------------------------------------------------------------------------
// K4: cam apply + pam combine + psi-conv + BN + sigmoid + x * da
// psi reconstructed as hi+lo (fp32-accurate).
// ---------------------------------------------------------------------------
__global__ __launch_bounds__(256) void k_final(
    const u16* __restrict__ psiB, const u16* __restrict__ psiLo,
    const float* __restrict__ att,
    const float* __restrict__ Oatt, const float* __restrict__ x,
    const float* __restrict__ psiw, const float* __restrict__ psib,
    const float* __restrict__ pg, const float* __restrict__ pbeta,
    const float* __restrict__ pm, const float* __restrict__ pv,
    const float* __restrict__ alpha, const float* __restrict__ camb,
    float* __restrict__ out)
{
    const int tid = threadIdx.x, tx = tid & 63, ty = tid >> 6;
    const int b = blockIdx.y, p0 = blockIdx.x * 64;
    __shared__ float tp[64][65];
    __shared__ float A[64][64];
    __shared__ float Zp[4][64];

#pragma unroll
    for (int r = 0; r < 16; ++r) {
        int c = ty * 16 + r;
        size_t idx = ((size_t)b * FI + c) * HW + p0 + tx;
        tp[c][tx] = b2f(psiB[idx]) + b2f(psiLo[idx]);
        A[c][tx]  = att[((size_t)b * 64 + c) * 64 + tx];
    }
    __syncthreads();

    const float al = alpha[0], cb = camb[0];
    const int c0 = __builtin_amdgcn_readfirstlane(ty * 16);
    float acc[16];
#pragma unroll
    for (int i = 0; i < 16; ++i) acc[i] = 0.f;
#pragma unroll 16
    for (int d = 0; d < 64; ++d) {
        float v = tp[d][tx];
#pragma unroll
        for (int i = 0; i < 16; ++i) acc[i] += A[c0 + i][d] * v;
    }
    float z = 0.f;
#pragma unroll
    for (int i = 0; i < 16; ++i) {
        int c = c0 + i;
        float ps  = tp[c][tx];
        float cam = cb * acc[i] + ps;
        float oa  = Oatt[((size_t)b * FI + c) * HW + p0 + tx];
        float pam = al * oa + ps;
        z += psiw[c] * (cam * pam);
    }
    Zp[ty][tx] = z;
    __syncthreads();
    float zt = Zp[0][tx] + Zp[1][tx] + Zp[2][tx] + Zp[3][tx] + psib[0];
    float inv = pg[0] * rsqrtf(pv[0] + EPS);
    float gate = (zt - pm[0]) * inv + pbeta[0];
    float da = 1.f / (1.f + __expf(-gate));

#pragma unroll 8
    for (int r = 0; r < 64; ++r) {
        int cl = ty + 4 * r;
        size_t idx = ((size_t)b * CIN + cl) * HW + p0 + tx;
        out[idx] = x[idx] * da;
    }
}

// ---------------------------------------------------------------------------
extern "C" void kernel_launch(void* const* d_in, const int* in_sizes, int n_in,
                              void* d_out, int out_size, void* d_ws, size_t ws_size,
                              hipStream_t stream)
{
    const float* g     = (const float*)d_in[0];
    const float* x     = (const float*)d_in[1];
    const float* Wg_w  = (const float*)d_in[2];
    const float* Wg_b  = (const float*)d_in[3];
    const float* bng_g = (const float*)d_in[4];
    const float* bng_b = (const float*)d_in[5];
    const float* bng_m = (const float*)d_in[6];
    const float* bng_v = (const float*)d_in[7];
    const float* Wx_w  = (const float*)d_in[8];
    const float* Wx_b  = (const float*)d_in[9];
    const float* bnx_g = (const float*)d_in[10];
    const float* bnx_b = (const float*)d_in[11];
    const float* bnx_m = (const float*)d_in[12];
    const float* bnx_v = (const float*)d_in[13];
    const float* psi_w = (const float*)d_in[14];
    const float* psi_b = (const float*)d_in[15];
    const float* bnp_g = (const float*)d_in[16];
    const float* bnp_b = (const float*)d_in[17];
    const float* bnp_m = (const float*)d_in[18];
    const float* bnp_v = (const float*)d_in[19];
    const float* pb_w  = (const float*)d_in[20];
    const float* pb_b  = (const float*)d_in[21];
    const float* pc_w  = (const float*)d_in[22];
    const float* pc_b  = (const float*)d_in[23];
    const float* pd_w  = (const float*)d_in[24];
    const float* pd_b  = (const float*)d_in[25];
    const float* alpha = (const float*)d_in[26];
    const float* camb  = (const float*)d_in[27];
    float* out = (float*)d_out;

    float* ws   = (float*)d_ws;
    // float-unit offsets; psiT+Gp region is dead by the time Oa is written,
    // so Oa overlays both.
    u16*  psiB  = (u16*)(ws);                 // fl [0,       1048576)
    u16*  psiLo = (u16*)(ws + 1048576);       // fl [1048576, 2097152)
    u16*  psiT  = (u16*)(ws + 2097152);       // fl [2097152, 3145728)
    float* Gp   = ws + 3145728;               // fl [3145728, 4194304)
    float* Oa   = ws + 2097152;               // fl [2097152, 4194304) overlay
    u16*  fbcT  = (u16*)(ws + 4194304);       // fl [4194304, 4456448)
    u16*  fdB   = (u16*)(ws + 4456448);       // fl [4456448, 5505024)
    float* att  = ws + 5505024;               // fl [5505024, 5537792)
    u16*  Wp    = (u16*)(ws + 5537792);       // fl [5537792, 5554176)
    float* Cp   = ws + 5554176;               // fl [5554176, 5554240)
    u16*  Wcat  = (u16*)(ws + 5554240);       // fl [5554240, 5556800)
    float* bcat = ws + 5556800;               // fl [5556800, 5556880) ~22.2 MB

    k_prep<<<dim3(16), 256, 0, stream>>>(Wg_w, Wg_b, bng_g, bng_b, bng_m, bng_v,
                                         Wx_w, Wx_b, bnx_g, bnx_b, bnx_m, bnx_v,
                                         pb_w, pb_b, pc_w, pc_b, pd_w, pd_b,
                                         Wp, Cp, Wcat, bcat);
    k_psi<<<dim3(64, 8), 256, 0, stream>>>(g, x, Wp, Cp, psiB, psiLo, psiT);
    k_fbcd<<<dim3(64, 8), 256, 0, stream>>>(psiT, Wcat, bcat, fbcT, fdB);
    k_gram<<<dim3(32, 8), 256, 0, stream>>>(psiB, psiLo, Gp);
    k_camsm<<<dim3(8, 4), 256, 0, stream>>>(Gp, att);
    k_pam<<<dim3(8, 64), 256, 0, stream>>>(fbcT, fdB, Oa);
    k_final<<<dim3(64, 8), 256, 0, stream>>>(psiB, psiLo, att, Oa, x, psi_w, psi_b,
                                             bnp_g, bnp_b, bnp_m, bnp_v, alpha, camb, out);
}

// Round 7
// 298.818 us; speedup vs baseline: 4.6102x; 1.0628x over previous
//
#include <hip/hip_runtime.h>
#include <hip/hip_bf16.h>
#include <math.h>

// Problem constants
#define BB 8
#define CIN 256
#define FI 64
#define HW 4096
#define C8 8
#define EPS 1e-5f

typedef __attribute__((ext_vector_type(8))) short bf16x8;
typedef __attribute__((ext_vector_type(4))) float f32x4;
typedef unsigned short u16;

static __device__ __forceinline__ u16 f2b(float x) {
    unsigned u = __builtin_bit_cast(unsigned, x);
    return (u16)((u + 0x8000u) >> 16);
}
static __device__ __forceinline__ unsigned pk2(float a, float b) {
    unsigned ua = __builtin_bit_cast(unsigned, a);
    unsigned ub = __builtin_bit_cast(unsigned, b);
    return ((ua + 0x8000u) >> 16) | ((ub + 0x8000u) & 0xffff0000u);
}
static __device__ __forceinline__ float b2f(u16 v) {
    return __builtin_bit_cast(float, ((unsigned)v) << 16);
}

// ---------------------------------------------------------------------------
// K0: fold BN into psi-conv weights (Wp bf16 [64][512], Cp fp32[64]) and
// build concatenated PAM weights (Wcat bf16 [80][64], bcat fp32[80]).
// ---------------------------------------------------------------------------
__global__ __launch_bounds__(256) void k_prep(
    const float* __restrict__ Wg, const float* __restrict__ Wgb,
    const float* __restrict__ gg, const float* __restrict__ gbeta,
    const float* __restrict__ gm, const float* __restrict__ gv,
    const float* __restrict__ Wx, const float* __restrict__ Wxb,
    const float* __restrict__ xg, const float* __restrict__ xbeta,
    const float* __restrict__ xm, const float* __restrict__ xv,
    const float* __restrict__ pbw, const float* __restrict__ pbb,
    const float* __restrict__ pcw, const float* __restrict__ pcb,
    const float* __restrict__ pdw, const float* __restrict__ pdb,
    u16* __restrict__ Wp, float* __restrict__ Cp,
    u16* __restrict__ Wcat, float* __restrict__ bcat)
{
    const int gid = blockIdx.x * 256 + threadIdx.x;
    for (int idx = gid; idx < FI * 512; idx += 4096) {
        int o = idx >> 9, k = idx & 511;
        float s, w;
        if (k < 256) { s = gg[o] * rsqrtf(gv[o] + EPS); w = Wg[o * 256 + k]; }
        else         { s = xg[o] * rsqrtf(xv[o] + EPS); w = Wx[o * 256 + k - 256]; }
        Wp[idx] = f2b(w * s);
    }
    for (int idx = gid; idx < 80 * 64; idx += 4096) {
        int row = idx >> 6, col = idx & 63;
        float w;
        if (row < 8)       w = pbw[row * 64 + col];
        else if (row < 16) w = pcw[(row - 8) * 64 + col];
        else               w = pdw[(row - 16) * 64 + col];
        Wcat[idx] = f2b(w);
    }
    if (blockIdx.x == 0) {
        int tid = threadIdx.x;
        if (tid < FI) {
            float ig = gg[tid] * rsqrtf(gv[tid] + EPS);
            float ix = xg[tid] * rsqrtf(xv[tid] + EPS);
            Cp[tid] = (Wgb[tid] - gm[tid]) * ig + gbeta[tid]
                    + (Wxb[tid] - xm[tid]) * ix + xbeta[tid];
        }
        if (tid >= 64 && tid < 144) {
            int r = tid - 64;
            bcat[r] = (r < 8) ? pbb[r] : (r < 16 ? pcb[r - 8] : pdb[r - 16]);
        }
    }
}

// ---------------------------------------------------------------------------
// K1: psi = relu(W' @ cat(g,x) + C) via bf16 MFMA, FUSED with fbcd:
// emits psiB/psiLo bf16 [B][64][4096], fbcT bf16 [B][4096][16],
// fdB bf16 [B][64][4096]. psi^T lives only in LDS.
// grid (64 px-tiles, 8 b) x 256
// ---------------------------------------------------------------------------
__global__ __launch_bounds__(256) void k_psi(
    const float* __restrict__ g, const float* __restrict__ x,
    const u16* __restrict__ Wp, const float* __restrict__ Cp,
    const u16* __restrict__ Wcat, const float* __restrict__ bcat,
    u16* __restrict__ psiB, u16* __restrict__ psiLo,
    u16* __restrict__ fbcT, u16* __restrict__ fdB)
{
    const int tid  = threadIdx.x;
    const int lane = tid & 63;
    const int w    = tid >> 6;
    const int n    = lane & 15;
    const int quad = lane >> 4;
    const int b    = blockIdx.y;
    const int p0   = blockIdx.x * 64;

    __shared__ u16 InT[64][72];   // in: [px][ch]; later psi^T, later Tfd [ch][px]
    __shared__ u16 Tbc[64][16];   // [px][out16]

    f32x4 acc[4];
#pragma unroll
    for (int mt = 0; mt < 4; ++mt) acc[mt] = (f32x4){0.f, 0.f, 0.f, 0.f};

    for (int kc = 0; kc < 8; ++kc) {
        const float* src = (kc < 4) ? g : x;
        const int ch0 = (kc & 3) * 64;
        __syncthreads();
#pragma unroll
        for (int r = 0; r < 4; ++r) {
            int ch = (tid >> 4) + r * 16;
            int px = (tid & 15) * 4;
            float4 v = *(const float4*)&src[((size_t)b * CIN + ch0 + ch) * HW + p0 + px];
            InT[px][ch]     = f2b(v.x);
            InT[px + 1][ch] = f2b(v.y);
            InT[px + 2][ch] = f2b(v.z);
            InT[px + 3][ch] = f2b(v.w);
        }
        __syncthreads();
#pragma unroll
        for (int ks = 0; ks < 2; ++ks) {
            const int kglob = kc * 64 + ks * 32;
            bf16x8 bfrag = *(const bf16x8*)&InT[w * 16 + n][ks * 32 + quad * 8];
#pragma unroll
            for (int mt = 0; mt < 4; ++mt) {
                bf16x8 af = *(const bf16x8*)&Wp[(mt * 16 + n) * 512 + kglob + quad * 8];
                acc[mt] = __builtin_amdgcn_mfma_f32_16x16x32_bf16(
                              af, bfrag, acc[mt], 0, 0, 0);
            }
        }
    }

    // bias + relu; store psiB(hi)+psiLo; build psi^T in InT
    float pv[4][4];
#pragma unroll
    for (int mt = 0; mt < 4; ++mt)
#pragma unroll
        for (int r = 0; r < 4; ++r) {
            int c = mt * 16 + quad * 4 + r;
            float v = acc[mt][r] + Cp[c];
            v = v > 0.f ? v : 0.f;
            pv[mt][r] = v;
            u16 hb = f2b(v);
            size_t idx = ((size_t)b * FI + c) * HW + p0 + w * 16 + n;
            psiB[idx]  = hb;
            psiLo[idx] = f2b(v - b2f(hb));
        }
    __syncthreads();   // staging reads done
#pragma unroll
    for (int mt = 0; mt < 4; ++mt) {
        *(unsigned*)&InT[w * 16 + n][mt * 16 + quad * 4]     = pk2(pv[mt][0], pv[mt][1]);
        *(unsigned*)&InT[w * 16 + n][mt * 16 + quad * 4 + 2] = pk2(pv[mt][2], pv[mt][3]);
    }
    __syncthreads();

    // fbcd MFMAs: A = psi^T rows (px), B = Wcat (L2-resident)
    f32x4 facc[5];
#pragma unroll
    for (int nt = 0; nt < 5; ++nt) facc[nt] = (f32x4){0.f, 0.f, 0.f, 0.f};
#pragma unroll
    for (int ks = 0; ks < 2; ++ks) {
        bf16x8 af = *(const bf16x8*)&InT[w * 16 + n][ks * 32 + quad * 8];
#pragma unroll
        for (int nt = 0; nt < 5; ++nt) {
            bf16x8 bf = *(const bf16x8*)&Wcat[(nt * 16 + n) * FI + ks * 32 + quad * 8];
            facc[nt] = __builtin_amdgcn_mfma_f32_16x16x32_bf16(af, bf, facc[nt], 0, 0, 0);
        }
    }
    __syncthreads();   // all psi^T reads done; reuse InT as Tfd [ch][px]

    {
        float bias = bcat[n];
#pragma unroll
        for (int r = 0; r < 4; ++r)
            Tbc[w * 16 + quad * 4 + r][n] = f2b(facc[0][r] + bias);
    }
#pragma unroll
    for (int nt = 1; nt < 5; ++nt) {
        int ch = (nt - 1) * 16 + n;
        float bias = bcat[nt * 16 + n];
        *(unsigned*)&InT[ch][w * 16 + quad * 4]     = pk2(facc[nt][0] + bias, facc[nt][1] + bias);
        *(unsigned*)&InT[ch][w * 16 + quad * 4 + 2] = pk2(facc[nt][2] + bias, facc[nt][3] + bias);
    }
    __syncthreads();
    {   // fbcT: 64 rows x 16 el
        int row = tid >> 2, part = tid & 3;
        uint2 v = *(const uint2*)&Tbc[row][part * 4];
        *(uint2*)&fbcT[((size_t)b * HW + p0 + row) * 16 + part * 4] = v;
    }
#pragma unroll
    for (int rep = 0; rep < 2; ++rep) {   // fdB: 64 ch x 64 px
        int t = rep * 256 + tid;
        int ch = t >> 3, seg = t & 7;
        bf16x8 v = *(const bf16x8*)&InT[ch][seg * 8];
        *(bf16x8*)&fdB[((size_t)b * FI + ch) * HW + p0 + seg * 8] = v;
    }
}

// ---------------------------------------------------------------------------
// K3a: Gram partials via compensated bf16 MFMA (hi*hi + hi*lo + lo*hi).
// grid (32 slices, 8 b) x 256 -> Gp[s][b][64][64]
// ---------------------------------------------------------------------------
__global__ __launch_bounds__(256) void k_gram(
    const u16* __restrict__ psiB, const u16* __restrict__ psiLo,
    float* __restrict__ Gp)
{
    const int tid  = threadIdx.x;
    const int lane = tid & 63;
    const int w    = tid >> 6;
    const int n    = lane & 15;
    const int quad = lane >> 4;
    const int s    = blockIdx.x;
    const int b    = blockIdx.y;

    f32x4 acc[4];
#pragma unroll
    for (int nt = 0; nt < 4; ++nt) acc[nt] = (f32x4){0.f, 0.f, 0.f, 0.f};

    for (int ks = 0; ks < 4; ++ks) {
        const int k0 = s * 128 + ks * 32;
        const size_t ra = ((size_t)b * FI + w * 16 + n) * HW + k0 + quad * 8;
        bf16x8 ah = *(const bf16x8*)&psiB[ra];
        bf16x8 al = *(const bf16x8*)&psiLo[ra];
#pragma unroll
        for (int nt = 0; nt < 4; ++nt) {
            const size_t rb = ((size_t)b * FI + nt * 16 + n) * HW + k0 + quad * 8;
            bf16x8 bh = *(const bf16x8*)&psiB[rb];
            bf16x8 bl = *(const bf16x8*)&psiLo[rb];
            acc[nt] = __builtin_amdgcn_mfma_f32_16x16x32_bf16(ah, bh, acc[nt], 0, 0, 0);
            acc[nt] = __builtin_amdgcn_mfma_f32_16x16x32_bf16(ah, bl, acc[nt], 0, 0, 0);
            acc[nt] = __builtin_amdgcn_mfma_f32_16x16x32_bf16(al, bh, acc[nt], 0, 0, 0);
        }
    }
#pragma unroll
    for (int nt = 0; nt < 4; ++nt)
#pragma unroll
        for (int r = 0; r < 4; ++r) {
            int i = w * 16 + quad * 4 + r;
            Gp[(((size_t)s * 8 + b) * 64 + i) * 64 + nt * 16 + n] = acc[nt][r];
        }
}

// ---------------------------------------------------------------------------
// K3b: CAM softmax of (rowmax - G).  grid (8 b, 4 grp) x 256
// ---------------------------------------------------------------------------
__global__ __launch_bounds__(256) void k_camsm(
    const float* __restrict__ Gp, float* __restrict__ att)
{
    const int tid = threadIdx.x, d = tid & 63, ty = tid >> 6;
    const int b = blockIdx.x, grp = blockIdx.y;
#pragma unroll 1
    for (int rr = 0; rr < 4; ++rr) {
        int i = grp * 16 + ty * 4 + rr;
        float gsum = 0.f;
#pragma unroll 1
        for (int s = 0; s < 32; ++s) gsum += Gp[(((size_t)s * 8 + b) * 64 + i) * 64 + d];
        float M = gsum;
#pragma unroll
        for (int msk = 1; msk < 64; msk <<= 1) M = fmaxf(M, __shfl_xor(M, msk));
        float a = M - gsum;
        float m2 = a;
#pragma unroll
        for (int msk = 1; msk < 64; msk <<= 1) m2 = fmaxf(m2, __shfl_xor(m2, msk));
        float p = __expf(a - m2);
        float ssum = p;
#pragma unroll
        for (int msk = 1; msk < 64; msk <<= 1) ssum += __shfl_xor(ssum, msk);
        att[((size_t)b * 64 + i) * 64 + d] = p / ssum;
    }
}

// ---------------------------------------------------------------------------
// K5: PAM flash attention, 2-way key split + register prefetch.
// grid (8 b, 64 qtile, 2 part) x 256. Emits normalized bf16 partials
// Opart[p][b][c][pix] + ml[p][b][pix] = (m, l).
// ---------------------------------------------------------------------------
__global__ __launch_bounds__(256) void k_pam(
    const u16* __restrict__ fbcT, const u16* __restrict__ fdB,
    u16* __restrict__ Opart, float* __restrict__ ml)
{
    const int tid  = threadIdx.x;
    const int lane = tid & 63;
    const int w    = tid >> 6;
    const int n    = lane & 15;
    const int quad = lane >> 4;
    const int b    = blockIdx.x;
    const int i0   = blockIdx.y * 64;
    const int p    = blockIdx.z;
    const int jstart = p * 32, jend = jstart + 32;

    __shared__ u16 Ks[68][8];      // [key][k0..7]; rows 64..67 zero pad
    __shared__ u16 Qs[64][32];     // [query][k]; cols 8..31 zero
    __shared__ u16 Vs[64][72];     // [chan][key]
    __shared__ u16 Ps[4][16][72];  // per-wave P^T [q_local][key]

    for (int t = tid; t < 64 * 16; t += 256) ((unsigned*)Qs)[t] = 0u;
    if (tid < 16) ((unsigned*)&Ks[64][0])[tid] = 0u;
    __syncthreads();
    if (tid < 64)
        *(bf16x8*)&Qs[tid][0] = *(const bf16x8*)&fbcT[((size_t)b * HW + i0 + tid) * 16];
    __syncthreads();
    const bf16x8 qfrag = *(const bf16x8*)&Qs[w * 16 + n][quad * 8];

    const int kkey = tid >> 1, khalf = tid & 1;
    const int vch  = tid >> 3, vseg  = tid & 7;

    // prefetch chunk jstart into regs
    uint2 kreg = make_uint2(0u, 0u);
    bf16x8 vreg0, vreg1;
    {
        const int j0 = jstart * 64;
        if (tid < 128)
            kreg = *(const uint2*)&fbcT[((size_t)b * HW + j0 + kkey) * 16 + 8 + khalf * 4];
        vreg0 = *(const bf16x8*)&fdB[((size_t)b * FI + vch) * HW + j0 + vseg * 8];
        vreg1 = *(const bf16x8*)&fdB[((size_t)b * FI + 32 + vch) * HW + j0 + vseg * 8];
    }

    f32x4 oacc[4];
#pragma unroll
    for (int mt = 0; mt < 4; ++mt) oacc[mt] = (f32x4){0.f, 0.f, 0.f, 0.f};
    float m = -1e30f, l = 0.f;   // l = per-lane partial (this quad's keys)

    for (int jc = jstart; jc < jend; ++jc) {
        __syncthreads();   // previous chunk's LDS readers done
        if (tid < 128) *(uint2*)&Ks[kkey][khalf * 4] = kreg;
        *(bf16x8*)&Vs[vch][vseg * 8]      = vreg0;
        *(bf16x8*)&Vs[32 + vch][vseg * 8] = vreg1;
        if (jc + 1 < jend) {   // prefetch next chunk (overlaps compute below)
            const int j0 = (jc + 1) * 64;
            if (tid < 128)
                kreg = *(const uint2*)&fbcT[((size_t)b * HW + j0 + kkey) * 16 + 8 + khalf * 4];
            vreg0 = *(const bf16x8*)&fdB[((size_t)b * FI + vch) * HW + j0 + vseg * 8];
            vreg1 = *(const bf16x8*)&fdB[((size_t)b * FI + 32 + vch) * HW + j0 + vseg * 8];
        }
        __syncthreads();

        // S^T tiles (quad overread hits finite data x zero Q cols)
        f32x4 s[4];
#pragma unroll
        for (int mt = 0; mt < 4; ++mt) {
            bf16x8 af = *(const bf16x8*)&Ks[mt * 16 + n + quad][0];
            s[mt] = __builtin_amdgcn_mfma_f32_16x16x32_bf16(
                        af, qfrag, (f32x4){0.f, 0.f, 0.f, 0.f}, 0, 0, 0);
        }

        float cmax = -1e30f;
#pragma unroll
        for (int mt = 0; mt < 4; ++mt)
            cmax = fmaxf(cmax, fmaxf(fmaxf(s[mt][0], s[mt][1]),
                                     fmaxf(s[mt][2], s[mt][3])));
        cmax = fmaxf(cmax, __shfl_xor(cmax, 16));
        cmax = fmaxf(cmax, __shfl_xor(cmax, 32));
        float mnew  = fmaxf(m, cmax);
        float scale = __expf(m - mnew);
        float psum  = 0.f;
        unsigned pw[4][2];
#pragma unroll
        for (int mt = 0; mt < 4; ++mt) {
            float e0 = __expf(s[mt][0] - mnew), e1 = __expf(s[mt][1] - mnew);
            float e2 = __expf(s[mt][2] - mnew), e3 = __expf(s[mt][3] - mnew);
            psum += (e0 + e1) + (e2 + e3);
            pw[mt][0] = pk2(e0, e1);
            pw[mt][1] = pk2(e2, e3);
        }
        l = l * scale + psum;   // deferred cross-quad combine
        m = mnew;

#pragma unroll
        for (int mt = 0; mt < 4; ++mt)
            *(uint2*)&Ps[w][n][mt * 16 + quad * 4] = make_uint2(pw[mt][0], pw[mt][1]);
        asm volatile("s_waitcnt lgkmcnt(0)" ::: "memory");

#pragma unroll
        for (int mt = 0; mt < 4; ++mt) {
            oacc[mt][0] *= scale; oacc[mt][1] *= scale;
            oacc[mt][2] *= scale; oacc[mt][3] *= scale;
        }
#pragma unroll
        for (int k0 = 0; k0 < 2; ++k0) {
            bf16x8 pf = *(const bf16x8*)&Ps[w][n][k0 * 32 + quad * 8];
#pragma unroll
            for (int mt = 0; mt < 4; ++mt) {
                bf16x8 vf = *(const bf16x8*)&Vs[mt * 16 + n][k0 * 32 + quad * 8];
                oacc[mt] = __builtin_amdgcn_mfma_f32_16x16x32_bf16(
                               vf, pf, oacc[mt], 0, 0, 0);
            }
        }
    }

    // combine l across quads (m already uniform per query)
    l += __shfl_xor(l, 16);
    l += __shfl_xor(l, 32);
    const float rl = 1.f / l;
#pragma unroll
    for (int mt = 0; mt < 4; ++mt)
#pragma unroll
        for (int r = 0; r < 4; ++r) {
            int c = mt * 16 + quad * 4 + r;
            Opart[(((size_t)p * 8 + b) * FI + c) * HW + i0 + w * 16 + n] =
                f2b(oacc[mt][r] * rl);
        }
    if (quad == 0)
        ((float2*)ml)[((size_t)p * 8 + b) * HW + i0 + w * 16 + n] = make_float2(m, l);
}

// ---------------------------------------------------------------------------
// K4: combine PAM partials + cam apply + psi-conv + BN + sigmoid + x * da
// ---------------------------------------------------------------------------
__global__ __launch_bounds__(256) void k_final(
    const u16* __restrict__ psiB, const u16* __restrict__ psiLo,
    const float* __restrict__ att,
    const u16* __restrict__ Opart, const float* __restrict__ ml,
    const float* __restrict__ x,
    const float* __restrict__ psiw, const float* __restrict__ psib,
    const float* __restrict__ pg, const float* __restrict__ pbeta,
    const float* __restrict__ pm, const float* __restrict__ pv,
    const float* __restrict__ alpha, const float* __restrict__ camb,
    float* __restrict__ out)
{
    const int tid = threadIdx.x, tx = tid & 63, ty = tid >> 6;
    const int b = blockIdx.y, p0 = blockIdx.x * 64;
    __shared__ float tp[64][65];
    __shared__ float A[64][64];
    __shared__ float Zp[4][64];

#pragma unroll
    for (int r = 0; r < 16; ++r) {
        int c = ty * 16 + r;
        size_t idx = ((size_t)b * FI + c) * HW + p0 + tx;
        tp[c][tx] = b2f(psiB[idx]) + b2f(psiLo[idx]);
        A[c][tx]  = att[((size_t)b * 64 + c) * 64 + tx];
    }
    __syncthreads();

    // flash-decoding combine weights for this pixel
    float2 ml0 = ((const float2*)ml)[((size_t)0 * 8 + b) * HW + p0 + tx];
    float2 ml1 = ((const float2*)ml)[((size_t)1 * 8 + b) * HW + p0 + tx];
    float M  = fmaxf(ml0.x, ml1.x);
    float w0 = ml0.y * __expf(ml0.x - M);
    float w1 = ml1.y * __expf(ml1.x - M);
    float winv = 1.f / (w0 + w1);
    w0 *= winv; w1 *= winv;

    const float al = alpha[0], cb = camb[0];
    const int c0 = __builtin_amdgcn_readfirstlane(ty * 16);
    float acc[16];
#pragma unroll
    for (int i = 0; i < 16; ++i) acc[i] = 0.f;
#pragma unroll 16
    for (int d = 0; d < 64; ++d) {
        float v = tp[d][tx];
#pragma unroll
        for (int i = 0; i < 16; ++i) acc[i] += A[c0 + i][d] * v;
    }
    float z = 0.f;
#pragma unroll
    for (int i = 0; i < 16; ++i) {
        int c = c0 + i;
        float ps  = tp[c][tx];
        float cam = cb * acc[i] + ps;
        float oa = w0 * b2f(Opart[(((size_t)0 * 8 + b) * FI + c) * HW + p0 + tx])
                 + w1 * b2f(Opart[(((size_t)1 * 8 + b) * FI + c) * HW + p0 + tx]);
        float pam = al * oa + ps;
        z += psiw[c] * (cam * pam);
    }
    Zp[ty][tx] = z;
    __syncthreads();
    float zt = Zp[0][tx] + Zp[1][tx] + Zp[2][tx] + Zp[3][tx] + psib[0];
    float inv = pg[0] * rsqrtf(pv[0] + EPS);
    float gate = (zt - pm[0]) * inv + pbeta[0];
    float da = 1.f / (1.f + __expf(-gate));

#pragma unroll 8
    for (int r = 0; r < 64; ++r) {
        int cl = ty + 4 * r;
        size_t idx = ((size_t)b * CIN + cl) * HW + p0 + tx;
        out[idx] = x[idx] * da;
    }
}

// ---------------------------------------------------------------------------
extern "C" void kernel_launch(void* const* d_in, const int* in_sizes, int n_in,
                              void* d_out, int out_size, void* d_ws, size_t ws_size,
                              hipStream_t stream)
{
    const float* g     = (const float*)d_in[0];
    const float* x     = (const float*)d_in[1];
    const float* Wg_w  = (const float*)d_in[2];
    const float* Wg_b  = (const float*)d_in[3];
    const float* bng_g = (const float*)d_in[4];
    const float* bng_b = (const float*)d_in[5];
    const float* bng_m = (const float*)d_in[6];
    const float* bng_v = (const float*)d_in[7];
    const float* Wx_w  = (const float*)d_in[8];
    const float* Wx_b  = (const float*)d_in[9];
    const float* bnx_g = (const float*)d_in[10];
    const float* bnx_b = (const float*)d_in[11];
    const float* bnx_m = (const float*)d_in[12];
    const float* bnx_v = (const float*)d_in[13];
    const float* psi_w = (const float*)d_in[14];
    const float* psi_b = (const float*)d_in[15];
    const float* bnp_g = (const float*)d_in[16];
    const float* bnp_b = (const float*)d_in[17];
    const float* bnp_m = (const float*)d_in[18];
    const float* bnp_v = (const float*)d_in[19];
    const float* pb_w  = (const float*)d_in[20];
    const float* pb_b  = (const float*)d_in[21];
    const float* pc_w  = (const float*)d_in[22];
    const float* pc_b  = (const float*)d_in[23];
    const float* pd_w  = (const float*)d_in[24];
    const float* pd_b  = (const float*)d_in[25];
    const float* alpha = (const float*)d_in[26];
    const float* camb  = (const float*)d_in[27];
    float* out = (float*)d_out;

    float* ws   = (float*)d_ws;
    // float-unit offsets. Opart overlays Gp (Gp dead after k_camsm).
    u16*  psiB  = (u16*)(ws);                 // fl [0,       1048576)
    u16*  psiLo = (u16*)(ws + 1048576);       // fl [1048576, 2097152)
    u16*  fbcT  = (u16*)(ws + 2097152);       // fl [2097152, 2359296)
    u16*  fdB   = (u16*)(ws + 2359296);       // fl [2359296, 3407872)
    float* att  = ws + 3407872;               // fl [3407872, 3440640)
    u16*  Wp    = (u16*)(ws + 3440640);       // fl [3440640, 3457024)
    float* Cp   = ws + 3457024;               // fl [3457024, 3457088)
    u16*  Wcat  = (u16*)(ws + 3457088);       // fl [3457088, 3459648)
    float* bcat = ws + 3459648;               // fl [3459648, 3459728)
    float* mlws = ws + 3459744;               // fl [3459744, 3590816)
    float* Gp   = ws + 3590816;               // fl [3590816, 4639392)
    u16*  Opart = (u16*)(ws + 3590816);       // fl [3590816, 5687968) overlay
                                              // total ~22.8 MB

    k_prep<<<dim3(16), 256, 0, stream>>>(Wg_w, Wg_b, bng_g, bng_b, bng_m, bng_v,
                                         Wx_w, Wx_b, bnx_g, bnx_b, bnx_m, bnx_v,
                                         pb_w, pb_b, pc_w, pc_b, pd_w, pd_b,
                                         Wp, Cp, Wcat, bcat);
    k_psi<<<dim3(64, 8), 256, 0, stream>>>(g, x, Wp, Cp, Wcat, bcat,
                                           psiB, psiLo, fbcT, fdB);
    k_gram<<<dim3(32, 8), 256, 0, stream>>>(psiB, psiLo, Gp);
    k_camsm<<<dim3(8, 4), 256, 0, stream>>>(Gp, att);
    k_pam<<<dim3(8, 64, 2), 256, 0, stream>>>(fbcT, fdB, Opart, mlws);
    k_final<<<dim3(64, 8), 256, 0, stream>>>(psiB, psiLo, att, Opart, mlws, x,
                                             psi_w, psi_b, bnp_g, bnp_b, bnp_m, bnp_v,
                                             alpha, camb, out);
}